// Round 1
// baseline (2324.056 us; speedup 1.0000x reference)
//
#include <hip/hip_runtime.h>
#include <hip/hip_bf16.h>

// CPSFMemcellAutoencoder: B=8, 256x256 input, N=16, S=128, M=32, T=131072.
// Workspace layout (requires ~260,083,712 bytes):
//   [0, 134217728)            a_s   : 8*128*256*256 bf16  (s-branch conv1 out; precision-insensitive, see analysis)
//   [134217728, 201326592)    t_star: 8*128*128*128 f32   ([T,128] token-major)
//   [201326592, 234881024)    a_n   : 8*16*256*256  f32
//   [234881024, 243269632)    z     : [T,16] f32
//   [243269632, 260046848)    wmat  : [T,32] f32
//   [260046848, 260050944)    WtW   : [32,32] f32 (atomic-accumulated; zeroed via memsetAsync)
//   [260050944, 260067328)    WtT   : [32,128] f32
//   [260067328, 260083712)    cvn   : [32,128] f32 (cell_v_new)
//   d0m  reuses [0, 67108864)        : [8,128,128,128] f32 (a_s dead by then)
//   dec1 reuses [67108864, 73400320) : [8,3,256,256] f32

#define ALPHA_F 1e-6f

__device__ __forceinline__ float silu_f(float x) {
    return x / (1.f + __expf(-x));
}

// ---------------- conv 3x3, Cin=3, stride 1, pad 1, + bias + silu ----------------
template<int CO, typename OT>
__global__ __launch_bounds__(256) void conv1_silu(
    const float* __restrict__ x, const float* __restrict__ wgt,
    const float* __restrict__ bias, OT* __restrict__ out)
{
    int idx = blockIdx.x * 256 + threadIdx.x;      // (b,h,w)
    int w = idx & 255, h = (idx >> 8) & 255, b = idx >> 16;
    const float* xb = x + (size_t)b * 3 * 65536;
    float in[27];
#pragma unroll
    for (int ci = 0; ci < 3; ci++)
#pragma unroll
        for (int ky = 0; ky < 3; ky++)
#pragma unroll
            for (int kx = 0; kx < 3; kx++) {
                int hh = h + ky - 1, ww = w + kx - 1;
                bool ok = ((unsigned)hh < 256u) && ((unsigned)ww < 256u);
                in[(ci * 3 + ky) * 3 + kx] = ok ? xb[(ci << 16) + (hh << 8) + ww] : 0.f;
            }
    OT* ob = out + (size_t)b * CO * 65536 + (h << 8) + w;
#pragma unroll 4
    for (int co = 0; co < CO; co++) {
        float acc = bias[co];          // uniform index -> s_load
#pragma unroll
        for (int k = 0; k < 27; k++) acc += in[k] * wgt[co * 27 + k];
        acc = silu_f(acc);
        if constexpr (sizeof(OT) == 2) ob[(size_t)co << 16] = __float2bfloat16(acc);
        else                           ob[(size_t)co << 16] = acc;
    }
}

// ------------- conv 3x3, stride 2, pad 1, + bias + silu, token-major out -------------
template<int CI, int CO, typename IT>
__global__ __launch_bounds__(256) void conv2s2_silu(
    const IT* __restrict__ in, const float* __restrict__ wgt,
    const float* __restrict__ bias, float* __restrict__ out)
{
    int idx = blockIdx.x * 256 + threadIdx.x;      // token (b,h2,w2)
    int w2 = idx & 127, h2 = (idx >> 7) & 127, b = idx >> 14;
    const IT* ib = in + (size_t)b * CI * 65536;
    float acc[CO];
#pragma unroll
    for (int co = 0; co < CO; co++) acc[co] = bias[co];
    int h0 = 2 * h2 - 1, w0 = 2 * w2 - 1;
    for (int ci = 0; ci < CI; ci++) {
        float t[9];
#pragma unroll
        for (int ky = 0; ky < 3; ky++)
#pragma unroll
            for (int kx = 0; kx < 3; kx++) {
                int hh = h0 + ky, ww = w0 + kx;
                bool ok = ((unsigned)hh < 256u) && ((unsigned)ww < 256u);
                float v = 0.f;
                if (ok) {
                    if constexpr (sizeof(IT) == 2)
                        v = __bfloat162float(ib[((size_t)ci << 16) + (hh << 8) + ww]);
                    else
                        v = ib[((size_t)ci << 16) + (hh << 8) + ww];
                }
                t[ky * 3 + kx] = v;
            }
#pragma unroll
        for (int co = 0; co < CO; co++)
#pragma unroll
            for (int k = 0; k < 9; k++)
                acc[co] += t[k] * wgt[(co * CI + ci) * 9 + k];   // uniform -> s_load
    }
    float* ob = out + (size_t)idx * CO;
#pragma unroll
    for (int co = 0; co < CO; co++) ob[co] = silu_f(acc[co]);
}

// ---------------- softmax(z @ cell_k^T / 4) -> w [T,32] ----------------
__global__ __launch_bounds__(256) void memcell_w_kern(
    const float* __restrict__ z, const float* __restrict__ ck, float* __restrict__ wout)
{
    int t = blockIdx.x * 256 + threadIdx.x;
    float zv[16];
    const float4* zp = (const float4*)(z + (size_t)t * 16);
#pragma unroll
    for (int i = 0; i < 4; i++) {
        float4 v = zp[i];
        zv[4 * i] = v.x; zv[4 * i + 1] = v.y; zv[4 * i + 2] = v.z; zv[4 * i + 3] = v.w;
    }
    float lg[32]; float mx = -1e30f;
#pragma unroll
    for (int m = 0; m < 32; m++) {
        float a = 0.f;
#pragma unroll
        for (int n = 0; n < 16; n++) a += zv[n] * ck[m * 16 + n];
        a *= 0.25f;
        lg[m] = a; mx = fmaxf(mx, a);
    }
    float s = 0.f;
#pragma unroll
    for (int m = 0; m < 32; m++) { lg[m] = __expf(lg[m] - mx); s += lg[m]; }
    float inv = 1.f / s;
    float4* wp = (float4*)(wout + (size_t)t * 32);
#pragma unroll
    for (int m = 0; m < 8; m++)
        wp[m] = make_float4(lg[4 * m] * inv, lg[4 * m + 1] * inv,
                            lg[4 * m + 2] * inv, lg[4 * m + 3] * inv);
}

// ---------------- WtW = w^T w [32,32], WtT = w^T t_star [32,128] ----------------
__global__ __launch_bounds__(256) void memcell_acc_kern(
    const float* __restrict__ wmat, const float* __restrict__ tstar,
    float* __restrict__ WtW, float* __restrict__ WtT)
{
    __shared__ float ws[64][32];
    __shared__ float ts[64][128];
    int tid = threadIdx.x;
    int sg = tid & 31, mg = tid >> 5;        // WtT tile: m0=mg*4, s0=sg*4
    int mW = tid & 31, m2 = (tid >> 5) * 4;  // WtW tile: (mW, m2..m2+3)
    float accT[16], accW[4];
#pragma unroll
    for (int i = 0; i < 16; i++) accT[i] = 0.f;
#pragma unroll
    for (int i = 0; i < 4; i++) accW[i] = 0.f;

    for (int c = blockIdx.x; c < 2048; c += 256) {   // 2048 chunks of 64 tokens
        size_t base = (size_t)c * 64;
        __syncthreads();
        {
            const float4* src = (const float4*)(wmat + base * 32);
            float4* dst = (float4*)&ws[0][0];
#pragma unroll
            for (int i = 0; i < 2; i++) dst[tid + 256 * i] = src[tid + 256 * i];
            const float4* src2 = (const float4*)(tstar + base * 128);
            float4* dst2 = (float4*)&ts[0][0];
#pragma unroll
            for (int i = 0; i < 8; i++) dst2[tid + 256 * i] = src2[tid + 256 * i];
        }
        __syncthreads();
        for (int t = 0; t < 64; t++) {
            float wv[4];
#pragma unroll
            for (int i = 0; i < 4; i++) wv[i] = ws[t][mg * 4 + i];   // broadcast
            float4 sv = *(const float4*)&ts[t][sg * 4];              // b128, conflict-free
#pragma unroll
            for (int i = 0; i < 4; i++) {
                accT[i * 4 + 0] += wv[i] * sv.x; accT[i * 4 + 1] += wv[i] * sv.y;
                accT[i * 4 + 2] += wv[i] * sv.z; accT[i * 4 + 3] += wv[i] * sv.w;
            }
            float wa = ws[t][mW];
            float4 wb = *(const float4*)&ws[t][m2];
            accW[0] += wa * wb.x; accW[1] += wa * wb.y;
            accW[2] += wa * wb.z; accW[3] += wa * wb.w;
        }
    }
#pragma unroll
    for (int i = 0; i < 4; i++)
#pragma unroll
        for (int j = 0; j < 4; j++)
            atomicAdd(&WtT[(mg * 4 + i) * 128 + sg * 4 + j], accT[i * 4 + j]);
#pragma unroll
    for (int j = 0; j < 4; j++)
        atomicAdd(&WtW[mW * 32 + m2 + j], accW[j]);
}

// ------- cell_v_new = cell_v + ALPHA*(WtT - WtW @ cell_v)  [32,128] -------
__global__ __launch_bounds__(256) void cvnew_kern(
    const float* __restrict__ cv, const float* __restrict__ WtW,
    const float* __restrict__ WtT, float* __restrict__ cvn)
{
    int idx = blockIdx.x * 256 + threadIdx.x;   // 4096
    int s = idx & 127, m = idx >> 7;
    float g = WtT[idx];
#pragma unroll
    for (int j = 0; j < 32; j++) g -= WtW[m * 32 + j] * cv[j * 128 + s];
    cvn[idx] = cv[idx] + ALPHA_F * g;
}

// ------- t_read = w @ cell_v_new, scattered to NCHW d0m [8,128,128,128] -------
__global__ __launch_bounds__(256) void memcell_read_kern(
    const float* __restrict__ wmat, const float* __restrict__ cvn, float* __restrict__ d0m)
{
    int t = blockIdx.x * 256 + threadIdx.x;
    int w2 = t & 127, h2 = (t >> 7) & 127, b = t >> 14;
    float wv[32];
    const float4* wp = (const float4*)(wmat + (size_t)t * 32);
#pragma unroll
    for (int i = 0; i < 8; i++) {
        float4 v = wp[i];
        wv[4 * i] = v.x; wv[4 * i + 1] = v.y; wv[4 * i + 2] = v.z; wv[4 * i + 3] = v.w;
    }
    float* ob = d0m + (size_t)b * 128 * 16384 + (h2 << 7) + w2;
    for (int s = 0; s < 128; s++) {
        float a = 0.f;
#pragma unroll
        for (int m = 0; m < 32; m++) a += wv[m] * cvn[m * 128 + s];  // uniform -> s_load
        ob[(size_t)s * 16384] = a;
    }
}

// ------- ConvTranspose2d(128->3, k4, s2, p1) + bias + silu -------
// Parity-specialized grid.y in [0,4): (ph,pw) uniform per block so weight
// indices scalarize to s_loads.
__global__ __launch_bounds__(256) void deconv_silu_kern(
    const float* __restrict__ in, const float* __restrict__ dw,
    const float* __restrict__ db, float* __restrict__ out)
{
    int idx = blockIdx.x * 256 + threadIdx.x;   // (b,h2,w2)
    int ph = blockIdx.y >> 1, pw = blockIdx.y & 1;
    int w2 = idx & 127, h2 = (idx >> 7) & 127, b = idx >> 14;
    int h = 2 * h2 + ph, w = 2 * w2 + pw;
    int ihs[2], khs[2], iws[2], kws[2];
    ihs[0] = ph ? h2     : h2 - 1;  khs[0] = ph ? 2 : 3;
    ihs[1] = ph ? h2 + 1 : h2;      khs[1] = ph ? 0 : 1;
    iws[0] = pw ? w2     : w2 - 1;  kws[0] = pw ? 2 : 3;
    iws[1] = pw ? w2 + 1 : w2;      kws[1] = pw ? 0 : 1;
    float a0 = db[0], a1 = db[1], a2 = db[2];
    const float* ib = in + (size_t)b * 128 * 16384;
#pragma unroll
    for (int i = 0; i < 2; i++) {
        if ((unsigned)ihs[i] >= 128u) continue;
#pragma unroll
        for (int j = 0; j < 2; j++) {
            if ((unsigned)iws[j] >= 128u) continue;
            const float* p = ib + (ihs[i] << 7) + iws[j];
            int wb = khs[i] * 4 + kws[j];      // uniform
            for (int ci = 0; ci < 128; ci++) {
                float v = p[(size_t)ci * 16384];
                a0 += v * dw[ci * 48 + wb];          // dw[ci][co][kh][kw]
                a1 += v * dw[ci * 48 + 16 + wb];
                a2 += v * dw[ci * 48 + 32 + wb];
            }
        }
    }
    size_t ob = (size_t)b * 3 * 65536 + ((size_t)h << 8) + w;
    out[ob]          = silu_f(a0);
    out[ob + 65536]  = silu_f(a1);
    out[ob + 131072] = silu_f(a2);
}

extern "C" void kernel_launch(void* const* d_in, const int* in_sizes, int n_in,
                              void* d_out, int out_size, void* d_ws, size_t ws_size,
                              hipStream_t stream)
{
    const float* x      = (const float*)d_in[0];
    const float* e0n_w1 = (const float*)d_in[1];
    const float* e0n_b1 = (const float*)d_in[2];
    const float* e0n_w2 = (const float*)d_in[3];
    const float* e0n_b2 = (const float*)d_in[4];
    const float* e0s_w1 = (const float*)d_in[5];
    const float* e0s_b1 = (const float*)d_in[6];
    const float* e0s_w2 = (const float*)d_in[7];
    const float* e0s_b2 = (const float*)d_in[8];
    const float* d0_dw  = (const float*)d_in[9];
    const float* d0_db  = (const float*)d_in[10];
    const float* d0_cw  = (const float*)d_in[11];
    const float* d0_cb  = (const float*)d_in[12];
    const float* cell_k = (const float*)d_in[13];
    const float* cell_v = (const float*)d_in[14];
    float* outp = (float*)d_out;

    char* ws = (char*)d_ws;
    __hip_bfloat16* a_s = (__hip_bfloat16*)(ws);
    float* t_star = (float*)(ws + 134217728);
    float* a_n    = (float*)(ws + 201326592);
    float* z      = (float*)(ws + 234881024);
    float* wmat   = (float*)(ws + 243269632);
    float* WtW    = (float*)(ws + 260046848);
    float* WtT    = (float*)(ws + 260050944);
    float* cvn    = (float*)(ws + 260067328);
    float* d0m    = (float*)(ws);               // reuse a_s region
    float* dec1   = (float*)(ws + 67108864);    // reuse a_s region (tail)

    // encoders
    conv1_silu<16, float><<<2048, 256, 0, stream>>>(x, e0n_w1, e0n_b1, a_n);
    conv2s2_silu<16, 16, float><<<512, 256, 0, stream>>>(a_n, e0n_w2, e0n_b2, z);
    conv1_silu<128, __hip_bfloat16><<<2048, 256, 0, stream>>>(x, e0s_w1, e0s_b1, a_s);
    conv2s2_silu<128, 128, __hip_bfloat16><<<512, 256, 0, stream>>>(a_s, e0s_w2, e0s_b2, t_star);
    // memcell
    memcell_w_kern<<<512, 256, 0, stream>>>(z, cell_k, wmat);
    hipMemsetAsync(WtW, 0, (1024 + 4096) * sizeof(float), stream);
    memcell_acc_kern<<<256, 256, 0, stream>>>(wmat, t_star, WtW, WtT);
    cvnew_kern<<<16, 256, 0, stream>>>(cell_v, WtW, WtT, cvn);
    memcell_read_kern<<<512, 256, 0, stream>>>(wmat, cvn, d0m);
    // decoder
    dim3 dg(512, 4);
    deconv_silu_kern<<<dg, 256, 0, stream>>>(d0m, d0_dw, d0_db, dec1);
    conv1_silu<3, float><<<2048, 256, 0, stream>>>(dec1, d0_cw, d0_cb, outp);
}

// Round 2
// 626.254 us; speedup vs baseline: 3.7110x; 3.7110x over previous
//
#include <hip/hip_runtime.h>
#include <hip/hip_bf16.h>

// CPSFMemcellAutoencoder: B=8, 256x256 input, N=16, S=128, M=32, T=131072.
// Workspace layout (~260 MB):
//   [0, 134217728)            a_s   : NHWC [8][256][256][128] bf16 (s-branch conv1 out)
//   [134217728, 201326592)    t_star: [T,128] f32 token-major
//   [201326592, 234881024)    a_n   : [8,16,256,256] f32; REUSED for Wt[9][128][128] bf16 after conv2_n
//   [234881024, 243269632)    z     : [T,16] f32
//   [243269632, 260046848)    wmat  : [T,32] f32
//   [260046848, 260050944)    WtW   : [32,32] f32
//   [260050944, 260067328)    WtT   : [32,128] f32
//   [260067328, 260083712)    cvn   : [32,128] f32
//   d0m  reuses [0, 67108864)        : [8,128,128,128] f32
//   dec1 reuses [67108864, 73400320) : [8,3,256,256] f32

#define ALPHA_F 1e-6f

typedef __attribute__((ext_vector_type(8))) short bf16x8;
typedef __attribute__((ext_vector_type(4))) float f32x4;

__device__ __forceinline__ float silu_f(float x) {
    return x / (1.f + __expf(-x));
}

// ---------------- conv 3x3, Cin=3, stride 1, pad 1, + bias + silu (NCHW f32 out) ----------------
template<int CO>
__global__ __launch_bounds__(256) void conv1_silu(
    const float* __restrict__ x, const float* __restrict__ wgt,
    const float* __restrict__ bias, float* __restrict__ out)
{
    int idx = blockIdx.x * 256 + threadIdx.x;      // (b,h,w)
    int w = idx & 255, h = (idx >> 8) & 255, b = idx >> 16;
    const float* xb = x + (size_t)b * 3 * 65536;
    float in[27];
#pragma unroll
    for (int ci = 0; ci < 3; ci++)
#pragma unroll
        for (int ky = 0; ky < 3; ky++)
#pragma unroll
            for (int kx = 0; kx < 3; kx++) {
                int hh = h + ky - 1, ww = w + kx - 1;
                bool ok = ((unsigned)hh < 256u) && ((unsigned)ww < 256u);
                in[(ci * 3 + ky) * 3 + kx] = ok ? xb[(ci << 16) + (hh << 8) + ww] : 0.f;
            }
    float* ob = out + (size_t)b * CO * 65536 + (h << 8) + w;
#pragma unroll 4
    for (int co = 0; co < CO; co++) {
        float acc = bias[co];          // uniform index -> s_load
#pragma unroll
        for (int k = 0; k < 27; k++) acc += in[k] * wgt[co * 27 + k];
        ob[(size_t)co << 16] = silu_f(acc);
    }
}

// ---------------- s-branch conv1: 3->128, NHWC bf16 output ----------------
__global__ __launch_bounds__(256) void conv1s_nhwc(
    const float* __restrict__ x, const float* __restrict__ wgt,
    const float* __restrict__ bias, __hip_bfloat16* __restrict__ out)
{
    int idx = blockIdx.x * 256 + threadIdx.x;      // (b,h,w)
    int w = idx & 255, h = (idx >> 8) & 255, b = idx >> 16;
    const float* xb = x + (size_t)b * 3 * 65536;
    float in[27];
#pragma unroll
    for (int ci = 0; ci < 3; ci++)
#pragma unroll
        for (int ky = 0; ky < 3; ky++)
#pragma unroll
            for (int kx = 0; kx < 3; kx++) {
                int hh = h + ky - 1, ww = w + kx - 1;
                bool ok = ((unsigned)hh < 256u) && ((unsigned)ww < 256u);
                in[(ci * 3 + ky) * 3 + kx] = ok ? xb[(ci << 16) + (hh << 8) + ww] : 0.f;
            }
    __hip_bfloat16* ob = out + (size_t)idx * 128;
#pragma unroll
    for (int j = 0; j < 16; j++) {
        union { __hip_bfloat16 hh[8]; float4 v; } u;
#pragma unroll
        for (int u8 = 0; u8 < 8; u8++) {
            int co = j * 8 + u8;
            float acc = bias[co];
#pragma unroll
            for (int k = 0; k < 27; k++) acc += in[k] * wgt[co * 27 + k];
            u.hh[u8] = __float2bfloat16(silu_f(acc));
        }
        ((float4*)ob)[j] = u.v;
    }
}

// ---------------- weight prep: Wt[pos][co][ci] bf16 from W[co][ci][ky][kx] f32 ----------------
__global__ __launch_bounds__(256) void wprep_kern(
    const float* __restrict__ w, __hip_bfloat16* __restrict__ wt)
{
    int i = blockIdx.x * 256 + threadIdx.x;        // 147456
    int pos = i >> 14, rem = i & 16383;
    int co = rem >> 7, ci = rem & 127;
    wt[i] = __float2bfloat16(w[co * 1152 + ci * 9 + pos]);
}

// ------------- conv2_s as implicit GEMM: M=T x N=128co x K=1152, bf16 MFMA -------------
// Tile: 64 tokens x 128 co per workgroup; 4 waves, each wave 64x32 (4m x 2n MFMAs).
#define LDSK 40   // padded k-stride (bf16 elems): 80B rows -> only 2-way bank aliasing (free)
__global__ __launch_bounds__(256) void conv2s_mfma(
    const __hip_bfloat16* __restrict__ a_s,   // NHWC [8][256][256][128]
    const __hip_bfloat16* __restrict__ wt,    // [9][128co][128ci]
    const float* __restrict__ bias, float* __restrict__ out)  // [T][128]
{
    __shared__ __align__(16) short As[64 * LDSK];
    __shared__ __align__(16) short Bs[128 * LDSK];
    int tid = threadIdx.x;
    int g = blockIdx.x;                 // 2048 tiles
    int b = g >> 8, h2 = (g >> 1) & 127, w2base = (g & 1) * 64;
    int lane = tid & 63, wave = tid >> 6;

    int tokA = tid >> 2, cqA = tid & 3;         // A staging: token, ci8-group
    int w2A = w2base + tokA;
    int mrow = lane & 15, koff8 = (lane >> 4) * 8;

    f32x4 acc[2][4];
#pragma unroll
    for (int i = 0; i < 2; i++)
#pragma unroll
        for (int j = 0; j < 4; j++)
#pragma unroll
            for (int r = 0; r < 4; r++) acc[i][j][r] = 0.f;

    const __hip_bfloat16* ab = a_s + (size_t)b * 65536 * 128;

    for (int pos = 0; pos < 9; pos++) {
        int ky = pos / 3, kx = pos - 3 * ky;    // uniform
        int y = 2 * h2 - 1 + ky;
        int x = 2 * w2A - 1 + kx;
        bool okA = ((unsigned)y < 256u) && ((unsigned)x < 256u);
        const __hip_bfloat16* ap = ab + (((size_t)y << 8) + x) * 128 + cqA * 8;
        const __hip_bfloat16* wp = wt + (size_t)pos * 16384;
#pragma unroll 1
        for (int cc = 0; cc < 4; cc++) {        // ci chunks of 32
            float4 av = make_float4(0.f, 0.f, 0.f, 0.f);
            if (okA) av = *(const float4*)(ap + cc * 32);
            int c1 = tid + 256;
            float4 b0 = *(const float4*)(wp + (size_t)(tid >> 2) * 128 + cc * 32 + (tid & 3) * 8);
            float4 b1 = *(const float4*)(wp + (size_t)(c1 >> 2) * 128 + cc * 32 + (c1 & 3) * 8);
            __syncthreads();                    // previous iter's LDS reads done
            *(float4*)&As[tokA * LDSK + cqA * 8] = av;
            *(float4*)&Bs[(tid >> 2) * LDSK + (tid & 3) * 8] = b0;
            *(float4*)&Bs[(c1 >> 2) * LDSK + (c1 & 3) * 8] = b1;
            __syncthreads();
            bf16x8 bfr[2], afr[4];
#pragma unroll
            for (int nt = 0; nt < 2; nt++)
                bfr[nt] = *(bf16x8*)&Bs[(wave * 32 + nt * 16 + mrow) * LDSK + koff8];
#pragma unroll
            for (int mt = 0; mt < 4; mt++)
                afr[mt] = *(bf16x8*)&As[(mt * 16 + mrow) * LDSK + koff8];
#pragma unroll
            for (int nt = 0; nt < 2; nt++)
#pragma unroll
                for (int mt = 0; mt < 4; mt++)
                    acc[nt][mt] = __builtin_amdgcn_mfma_f32_16x16x32_bf16(
                        afr[mt], bfr[nt], acc[nt][mt], 0, 0, 0);
        }
    }
    // epilogue: D[row=m=(lane>>4)*4+r][col=n=lane&15]
    int rowg = (lane >> 4) * 4;
    size_t tbase = (size_t)g * 64;
#pragma unroll
    for (int nt = 0; nt < 2; nt++) {
        int co = wave * 32 + nt * 16 + (lane & 15);
        float bv = bias[co];
#pragma unroll
        for (int mt = 0; mt < 4; mt++)
#pragma unroll
            for (int r = 0; r < 4; r++) {
                int m = mt * 16 + rowg + r;
                out[(tbase + m) * 128 + co] = silu_f(acc[nt][mt][r] + bv);
            }
    }
}

// ------------- conv 3x3, stride 2, pad 1, + bias + silu, token-major out (n-branch) -------------
template<int CI, int CO>
__global__ __launch_bounds__(256) void conv2s2_silu(
    const float* __restrict__ in, const float* __restrict__ wgt,
    const float* __restrict__ bias, float* __restrict__ out)
{
    int idx = blockIdx.x * 256 + threadIdx.x;      // token (b,h2,w2)
    int w2 = idx & 127, h2 = (idx >> 7) & 127, b = idx >> 14;
    const float* ib = in + (size_t)b * CI * 65536;
    float acc[CO];
#pragma unroll
    for (int co = 0; co < CO; co++) acc[co] = bias[co];
    int h0 = 2 * h2 - 1, w0 = 2 * w2 - 1;
    for (int ci = 0; ci < CI; ci++) {
        float t[9];
#pragma unroll
        for (int ky = 0; ky < 3; ky++)
#pragma unroll
            for (int kx = 0; kx < 3; kx++) {
                int hh = h0 + ky, ww = w0 + kx;
                bool ok = ((unsigned)hh < 256u) && ((unsigned)ww < 256u);
                t[ky * 3 + kx] = ok ? ib[((size_t)ci << 16) + (hh << 8) + ww] : 0.f;
            }
#pragma unroll
        for (int co = 0; co < CO; co++)
#pragma unroll
            for (int k = 0; k < 9; k++)
                acc[co] += t[k] * wgt[(co * CI + ci) * 9 + k];   // uniform -> s_load
    }
    float* ob = out + (size_t)idx * CO;
#pragma unroll
    for (int co = 0; co < CO; co++) ob[co] = silu_f(acc[co]);
}

// ---------------- softmax(z @ cell_k^T / 4) -> w [T,32] ----------------
__global__ __launch_bounds__(256) void memcell_w_kern(
    const float* __restrict__ z, const float* __restrict__ ck, float* __restrict__ wout)
{
    int t = blockIdx.x * 256 + threadIdx.x;
    float zv[16];
    const float4* zp = (const float4*)(z + (size_t)t * 16);
#pragma unroll
    for (int i = 0; i < 4; i++) {
        float4 v = zp[i];
        zv[4 * i] = v.x; zv[4 * i + 1] = v.y; zv[4 * i + 2] = v.z; zv[4 * i + 3] = v.w;
    }
    float lg[32]; float mx = -1e30f;
#pragma unroll
    for (int m = 0; m < 32; m++) {
        float a = 0.f;
#pragma unroll
        for (int n = 0; n < 16; n++) a += zv[n] * ck[m * 16 + n];
        a *= 0.25f;
        lg[m] = a; mx = fmaxf(mx, a);
    }
    float s = 0.f;
#pragma unroll
    for (int m = 0; m < 32; m++) { lg[m] = __expf(lg[m] - mx); s += lg[m]; }
    float inv = 1.f / s;
    float4* wp = (float4*)(wout + (size_t)t * 32);
#pragma unroll
    for (int m = 0; m < 8; m++)
        wp[m] = make_float4(lg[4 * m] * inv, lg[4 * m + 1] * inv,
                            lg[4 * m + 2] * inv, lg[4 * m + 3] * inv);
}

// ---------------- WtW = w^T w [32,32], WtT = w^T t_star [32,128] ----------------
__global__ __launch_bounds__(256) void memcell_acc_kern(
    const float* __restrict__ wmat, const float* __restrict__ tstar,
    float* __restrict__ WtW, float* __restrict__ WtT)
{
    __shared__ float ws[64][32];
    __shared__ float ts[64][128];
    int tid = threadIdx.x;
    int sg = tid & 31, mg = tid >> 5;        // WtT tile
    int mW = tid & 31, m2 = (tid >> 5) * 4;  // WtW tile
    float accT[16], accW[4];
#pragma unroll
    for (int i = 0; i < 16; i++) accT[i] = 0.f;
#pragma unroll
    for (int i = 0; i < 4; i++) accW[i] = 0.f;

    for (int c = blockIdx.x; c < 2048; c += 256) {
        size_t base = (size_t)c * 64;
        __syncthreads();
        {
            const float4* src = (const float4*)(wmat + base * 32);
            float4* dst = (float4*)&ws[0][0];
#pragma unroll
            for (int i = 0; i < 2; i++) dst[tid + 256 * i] = src[tid + 256 * i];
            const float4* src2 = (const float4*)(tstar + base * 128);
            float4* dst2 = (float4*)&ts[0][0];
#pragma unroll
            for (int i = 0; i < 8; i++) dst2[tid + 256 * i] = src2[tid + 256 * i];
        }
        __syncthreads();
        for (int t = 0; t < 64; t++) {
            float wv[4];
#pragma unroll
            for (int i = 0; i < 4; i++) wv[i] = ws[t][mg * 4 + i];
            float4 sv = *(const float4*)&ts[t][sg * 4];
#pragma unroll
            for (int i = 0; i < 4; i++) {
                accT[i * 4 + 0] += wv[i] * sv.x; accT[i * 4 + 1] += wv[i] * sv.y;
                accT[i * 4 + 2] += wv[i] * sv.z; accT[i * 4 + 3] += wv[i] * sv.w;
            }
            float wa = ws[t][mW];
            float4 wb = *(const float4*)&ws[t][m2];
            accW[0] += wa * wb.x; accW[1] += wa * wb.y;
            accW[2] += wa * wb.z; accW[3] += wa * wb.w;
        }
    }
#pragma unroll
    for (int i = 0; i < 4; i++)
#pragma unroll
        for (int j = 0; j < 4; j++)
            atomicAdd(&WtT[(mg * 4 + i) * 128 + sg * 4 + j], accT[i * 4 + j]);
#pragma unroll
    for (int j = 0; j < 4; j++)
        atomicAdd(&WtW[mW * 32 + m2 + j], accW[j]);
}

// ------- cell_v_new = cell_v + ALPHA*(WtT - WtW @ cell_v)  [32,128] -------
__global__ __launch_bounds__(256) void cvnew_kern(
    const float* __restrict__ cv, const float* __restrict__ WtW,
    const float* __restrict__ WtT, float* __restrict__ cvn)
{
    int idx = blockIdx.x * 256 + threadIdx.x;   // 4096
    int s = idx & 127, m = idx >> 7;
    float g = WtT[idx];
#pragma unroll
    for (int j = 0; j < 32; j++) g -= WtW[m * 32 + j] * cv[j * 128 + s];
    cvn[idx] = cv[idx] + ALPHA_F * g;
}

// ------- t_read = w @ cell_v_new, scattered to NCHW d0m [8,128,128,128] -------
__global__ __launch_bounds__(256) void memcell_read_kern(
    const float* __restrict__ wmat, const float* __restrict__ cvn, float* __restrict__ d0m)
{
    int t = blockIdx.x * 256 + threadIdx.x;
    int w2 = t & 127, h2 = (t >> 7) & 127, b = t >> 14;
    float wv[32];
    const float4* wp = (const float4*)(wmat + (size_t)t * 32);
#pragma unroll
    for (int i = 0; i < 8; i++) {
        float4 v = wp[i];
        wv[4 * i] = v.x; wv[4 * i + 1] = v.y; wv[4 * i + 2] = v.z; wv[4 * i + 3] = v.w;
    }
    float* ob = d0m + (size_t)b * 128 * 16384 + (h2 << 7) + w2;
    for (int s = 0; s < 128; s++) {
        float a = 0.f;
#pragma unroll
        for (int m = 0; m < 32; m++) a += wv[m] * cvn[m * 128 + s];  // uniform -> s_load
        ob[(size_t)s * 16384] = a;
    }
}

// ------- ConvTranspose2d(128->3, k4, s2, p1) + bias + silu -------
__global__ __launch_bounds__(256) void deconv_silu_kern(
    const float* __restrict__ in, const float* __restrict__ dw,
    const float* __restrict__ db, float* __restrict__ out)
{
    int idx = blockIdx.x * 256 + threadIdx.x;   // (b,h2,w2)
    int ph = blockIdx.y >> 1, pw = blockIdx.y & 1;
    int w2 = idx & 127, h2 = (idx >> 7) & 127, b = idx >> 14;
    int h = 2 * h2 + ph, w = 2 * w2 + pw;
    int ihs[2], khs[2], iws[2], kws[2];
    ihs[0] = ph ? h2     : h2 - 1;  khs[0] = ph ? 2 : 3;
    ihs[1] = ph ? h2 + 1 : h2;      khs[1] = ph ? 0 : 1;
    iws[0] = pw ? w2     : w2 - 1;  kws[0] = pw ? 2 : 3;
    iws[1] = pw ? w2 + 1 : w2;      kws[1] = pw ? 0 : 1;
    float a0 = db[0], a1 = db[1], a2 = db[2];
    const float* ib = in + (size_t)b * 128 * 16384;
#pragma unroll
    for (int i = 0; i < 2; i++) {
        if ((unsigned)ihs[i] >= 128u) continue;
#pragma unroll
        for (int j = 0; j < 2; j++) {
            if ((unsigned)iws[j] >= 128u) continue;
            const float* p = ib + (ihs[i] << 7) + iws[j];
            int wb = khs[i] * 4 + kws[j];      // uniform
            for (int ci = 0; ci < 128; ci++) {
                float v = p[(size_t)ci * 16384];
                a0 += v * dw[ci * 48 + wb];
                a1 += v * dw[ci * 48 + 16 + wb];
                a2 += v * dw[ci * 48 + 32 + wb];
            }
        }
    }
    size_t ob = (size_t)b * 3 * 65536 + ((size_t)h << 8) + w;
    out[ob]          = silu_f(a0);
    out[ob + 65536]  = silu_f(a1);
    out[ob + 131072] = silu_f(a2);
}

extern "C" void kernel_launch(void* const* d_in, const int* in_sizes, int n_in,
                              void* d_out, int out_size, void* d_ws, size_t ws_size,
                              hipStream_t stream)
{
    const float* x      = (const float*)d_in[0];
    const float* e0n_w1 = (const float*)d_in[1];
    const float* e0n_b1 = (const float*)d_in[2];
    const float* e0n_w2 = (const float*)d_in[3];
    const float* e0n_b2 = (const float*)d_in[4];
    const float* e0s_w1 = (const float*)d_in[5];
    const float* e0s_b1 = (const float*)d_in[6];
    const float* e0s_w2 = (const float*)d_in[7];
    const float* e0s_b2 = (const float*)d_in[8];
    const float* d0_dw  = (const float*)d_in[9];
    const float* d0_db  = (const float*)d_in[10];
    const float* d0_cw  = (const float*)d_in[11];
    const float* d0_cb  = (const float*)d_in[12];
    const float* cell_k = (const float*)d_in[13];
    const float* cell_v = (const float*)d_in[14];
    float* outp = (float*)d_out;

    char* ws = (char*)d_ws;
    __hip_bfloat16* a_s = (__hip_bfloat16*)(ws);
    float* t_star = (float*)(ws + 134217728);
    float* a_n    = (float*)(ws + 201326592);
    __hip_bfloat16* wt2 = (__hip_bfloat16*)(ws + 201326592);  // reuses a_n after conv2_n
    float* z      = (float*)(ws + 234881024);
    float* wmat   = (float*)(ws + 243269632);
    float* WtW    = (float*)(ws + 260046848);
    float* WtT    = (float*)(ws + 260050944);
    float* cvn    = (float*)(ws + 260067328);
    float* d0m    = (float*)(ws);               // reuse a_s region
    float* dec1   = (float*)(ws + 67108864);    // reuse a_s region (tail)

    // n-branch encoder (a_n dead after conv2s2_silu)
    conv1_silu<16><<<2048, 256, 0, stream>>>(x, e0n_w1, e0n_b1, a_n);
    conv2s2_silu<16, 16><<<512, 256, 0, stream>>>(a_n, e0n_w2, e0n_b2, z);
    // s-branch encoder: NHWC conv1 -> MFMA implicit-GEMM conv2
    wprep_kern<<<576, 256, 0, stream>>>(e0s_w2, wt2);
    conv1s_nhwc<<<2048, 256, 0, stream>>>(x, e0s_w1, e0s_b1, a_s);
    conv2s_mfma<<<2048, 256, 0, stream>>>(a_s, wt2, e0s_b2, t_star);
    // memcell
    memcell_w_kern<<<512, 256, 0, stream>>>(z, cell_k, wmat);
    hipMemsetAsync(WtW, 0, (1024 + 4096) * sizeof(float), stream);
    memcell_acc_kern<<<256, 256, 0, stream>>>(wmat, t_star, WtW, WtT);
    cvnew_kern<<<16, 256, 0, stream>>>(cell_v, WtW, WtT, cvn);
    memcell_read_kern<<<512, 256, 0, stream>>>(wmat, cvn, d0m);
    // decoder
    dim3 dg(512, 4);
    deconv_silu_kern<<<dg, 256, 0, stream>>>(d0m, d0_dw, d0_db, dec1);
    conv1_silu<3><<<2048, 256, 0, stream>>>(dec1, d0_cw, d0_cb, outp);
}

// Round 3
// 570.490 us; speedup vs baseline: 4.0738x; 1.0977x over previous
//
#include <hip/hip_runtime.h>
#include <hip/hip_bf16.h>

// CPSFMemcellAutoencoder: B=8, 256x256 input, N=16, S=128, M=32, T=131072.
// Workspace layout (~260 MB):
//   [0, 134217728)            a_s   : NC8HW8 [8][16 cig][65536 hw][8 ci] bf16 (s-branch conv1 out)
//   [134217728, 201326592)    t_star: [T,128] f32 token-major
//   [201326592, 234881024)    a_n   : [8,16,256,256] f32; REUSED for Wt[9][128][128] bf16 after conv2_n
//   [234881024, 243269632)    z     : [T,16] f32
//   [243269632, 260046848)    wmat  : [T,32] f32
//   [260046848, 260050944)    WtW   : [32,32] f32
//   [260050944, 260067328)    WtT   : [32,128] f32
//   [260067328, 260083712)    cvn   : [32,128] f32
//   d0m  reuses [0, 67108864)        : [8,128,128,128] f32
//   dec1 reuses [67108864, 73400320) : [8,3,256,256] f32

#define ALPHA_F 1e-6f

typedef __attribute__((ext_vector_type(8))) short bf16x8;
typedef __attribute__((ext_vector_type(4))) float f32x4;

__device__ __forceinline__ float silu_f(float x) {
    return x / (1.f + __expf(-x));
}

// ---------------- conv 3x3, Cin=3, stride 1, pad 1, + bias + silu (NCHW f32 out) ----------------
template<int CO>
__global__ __launch_bounds__(256) void conv1_silu(
    const float* __restrict__ x, const float* __restrict__ wgt,
    const float* __restrict__ bias, float* __restrict__ out)
{
    int idx = blockIdx.x * 256 + threadIdx.x;      // (b,h,w)
    int w = idx & 255, h = (idx >> 8) & 255, b = idx >> 16;
    const float* xb = x + (size_t)b * 3 * 65536;
    float in[27];
#pragma unroll
    for (int ci = 0; ci < 3; ci++)
#pragma unroll
        for (int ky = 0; ky < 3; ky++)
#pragma unroll
            for (int kx = 0; kx < 3; kx++) {
                int hh = h + ky - 1, ww = w + kx - 1;
                bool ok = ((unsigned)hh < 256u) && ((unsigned)ww < 256u);
                in[(ci * 3 + ky) * 3 + kx] = ok ? xb[(ci << 16) + (hh << 8) + ww] : 0.f;
            }
    float* ob = out + (size_t)b * CO * 65536 + (h << 8) + w;
#pragma unroll 4
    for (int co = 0; co < CO; co++) {
        float acc = bias[co];          // uniform index -> s_load
#pragma unroll
        for (int k = 0; k < 27; k++) acc += in[k] * wgt[co * 27 + k];
        ob[(size_t)co << 16] = silu_f(acc);
    }
}

// ---------------- s-branch conv1: 3->128, NC8HW8 bf16 output ----------------
// out float4-index = (b*16 + cig)*65536 + hw  -> consecutive lanes write
// consecutive 16B: fully coalesced, full-line coverage.
__global__ __launch_bounds__(256) void conv1s_nhwc(
    const float* __restrict__ x, const float* __restrict__ wgt,
    const float* __restrict__ bias, __hip_bfloat16* __restrict__ out)
{
    int idx = blockIdx.x * 256 + threadIdx.x;      // (b,h,w)
    int w = idx & 255, h = (idx >> 8) & 255, b = idx >> 16;
    int hw = (h << 8) + w;
    const float* xb = x + (size_t)b * 3 * 65536;
    float in[27];
#pragma unroll
    for (int ci = 0; ci < 3; ci++)
#pragma unroll
        for (int ky = 0; ky < 3; ky++)
#pragma unroll
            for (int kx = 0; kx < 3; kx++) {
                int hh = h + ky - 1, ww = w + kx - 1;
                bool ok = ((unsigned)hh < 256u) && ((unsigned)ww < 256u);
                in[(ci * 3 + ky) * 3 + kx] = ok ? xb[(ci << 16) + (hh << 8) + ww] : 0.f;
            }
    float4* ob = (float4*)out + (size_t)b * 16 * 65536 + hw;
#pragma unroll
    for (int j = 0; j < 16; j++) {
        union { __hip_bfloat16 hh[8]; float4 v; } u;
#pragma unroll
        for (int u8 = 0; u8 < 8; u8++) {
            int co = j * 8 + u8;
            float acc = bias[co];
#pragma unroll
            for (int k = 0; k < 27; k++) acc += in[k] * wgt[co * 27 + k];
            u.hh[u8] = __float2bfloat16(silu_f(acc));
        }
        ob[(size_t)j * 65536] = u.v;
    }
}

// ---------------- weight prep: Wt[pos][co][ci] bf16 from W[co][ci][ky][kx] f32 ----------------
__global__ __launch_bounds__(256) void wprep_kern(
    const float* __restrict__ w, __hip_bfloat16* __restrict__ wt)
{
    int i = blockIdx.x * 256 + threadIdx.x;        // 147456
    int pos = i >> 14, rem = i & 16383;
    int co = rem >> 7, ci = rem & 127;
    wt[i] = __float2bfloat16(w[co * 1152 + ci * 9 + pos]);
}

// ------------- conv2_s as implicit GEMM: M=T x N=128co x K=1152, bf16 MFMA -------------
// Tile: 64 tokens x 128 co per workgroup; 4 waves, each wave 64x32 (4m x 2n MFMAs).
#define LDSK 40   // padded k-stride (bf16 elems): 80B rows -> only 2-way bank aliasing (free)
__global__ __launch_bounds__(256) void conv2s_mfma(
    const __hip_bfloat16* __restrict__ a_s,   // NC8HW8 [8][16][65536][8]
    const __hip_bfloat16* __restrict__ wt,    // [9][128co][128ci]
    const float* __restrict__ bias, float* __restrict__ out)  // [T][128]
{
    __shared__ __align__(16) short As[64 * LDSK];
    __shared__ __align__(16) short Bs[128 * LDSK];
    int tid = threadIdx.x;
    int g = blockIdx.x;                 // 2048 tiles
    int b = g >> 8, h2 = (g >> 1) & 127, w2base = (g & 1) * 64;
    int lane = tid & 63, wave = tid >> 6;

    int tokA = tid >> 2, cqA = tid & 3;         // A staging: token, ci8-group
    int w2A = w2base + tokA;
    int mrow = lane & 15, koff8 = (lane >> 4) * 8;

    f32x4 acc[2][4];
#pragma unroll
    for (int i = 0; i < 2; i++)
#pragma unroll
        for (int j = 0; j < 4; j++)
#pragma unroll
            for (int r = 0; r < 4; r++) acc[i][j][r] = 0.f;

    const float4* ab8 = (const float4*)a_s + (size_t)b * 16 * 65536;

    for (int pos = 0; pos < 9; pos++) {
        int ky = pos / 3, kx = pos - 3 * ky;    // uniform
        int y = 2 * h2 - 1 + ky;
        int x = 2 * w2A - 1 + kx;
        bool okA = ((unsigned)y < 256u) && ((unsigned)x < 256u);
        int pix = (y << 8) + x;
        const __hip_bfloat16* wp = wt + (size_t)pos * 16384;
#pragma unroll 1
        for (int cc = 0; cc < 4; cc++) {        // ci chunks of 32
            float4 av = make_float4(0.f, 0.f, 0.f, 0.f);
            if (okA) av = ab8[(size_t)(cc * 4 + cqA) * 65536 + pix];
            int c1 = tid + 256;
            float4 b0 = *(const float4*)(wp + (size_t)(tid >> 2) * 128 + cc * 32 + (tid & 3) * 8);
            float4 b1 = *(const float4*)(wp + (size_t)(c1 >> 2) * 128 + cc * 32 + (c1 & 3) * 8);
            __syncthreads();                    // previous iter's LDS reads done
            *(float4*)&As[tokA * LDSK + cqA * 8] = av;
            *(float4*)&Bs[(tid >> 2) * LDSK + (tid & 3) * 8] = b0;
            *(float4*)&Bs[(c1 >> 2) * LDSK + (c1 & 3) * 8] = b1;
            __syncthreads();
            bf16x8 bfr[2], afr[4];
#pragma unroll
            for (int nt = 0; nt < 2; nt++)
                bfr[nt] = *(bf16x8*)&Bs[(wave * 32 + nt * 16 + mrow) * LDSK + koff8];
#pragma unroll
            for (int mt = 0; mt < 4; mt++)
                afr[mt] = *(bf16x8*)&As[(mt * 16 + mrow) * LDSK + koff8];
#pragma unroll
            for (int nt = 0; nt < 2; nt++)
#pragma unroll
                for (int mt = 0; mt < 4; mt++)
                    acc[nt][mt] = __builtin_amdgcn_mfma_f32_16x16x32_bf16(
                        afr[mt], bfr[nt], acc[nt][mt], 0, 0, 0);
        }
    }
    // epilogue: D[row=m=(lane>>4)*4+r][col=n=lane&15]
    int rowg = (lane >> 4) * 4;
    size_t tbase = (size_t)g * 64;
#pragma unroll
    for (int nt = 0; nt < 2; nt++) {
        int co = wave * 32 + nt * 16 + (lane & 15);
        float bv = bias[co];
#pragma unroll
        for (int mt = 0; mt < 4; mt++)
#pragma unroll
            for (int r = 0; r < 4; r++) {
                int m = mt * 16 + rowg + r;
                out[(tbase + m) * 128 + co] = silu_f(acc[nt][mt][r] + bv);
            }
    }
}

// ------------- conv 3x3, stride 2, pad 1, + bias + silu, token-major out (n-branch) -------------
template<int CI, int CO>
__global__ __launch_bounds__(256) void conv2s2_silu(
    const float* __restrict__ in, const float* __restrict__ wgt,
    const float* __restrict__ bias, float* __restrict__ out)
{
    int idx = blockIdx.x * 256 + threadIdx.x;      // token (b,h2,w2)
    int w2 = idx & 127, h2 = (idx >> 7) & 127, b = idx >> 14;
    const float* ib = in + (size_t)b * CI * 65536;
    float acc[CO];
#pragma unroll
    for (int co = 0; co < CO; co++) acc[co] = bias[co];
    int h0 = 2 * h2 - 1, w0 = 2 * w2 - 1;
    for (int ci = 0; ci < CI; ci++) {
        float t[9];
#pragma unroll
        for (int ky = 0; ky < 3; ky++)
#pragma unroll
            for (int kx = 0; kx < 3; kx++) {
                int hh = h0 + ky, ww = w0 + kx;
                bool ok = ((unsigned)hh < 256u) && ((unsigned)ww < 256u);
                t[ky * 3 + kx] = ok ? ib[((size_t)ci << 16) + (hh << 8) + ww] : 0.f;
            }
#pragma unroll
        for (int co = 0; co < CO; co++)
#pragma unroll
            for (int k = 0; k < 9; k++)
                acc[co] += t[k] * wgt[(co * CI + ci) * 9 + k];   // uniform -> s_load
    }
    float* ob = out + (size_t)idx * CO;
#pragma unroll
    for (int co = 0; co < CO; co++) ob[co] = silu_f(acc[co]);
}

// ---------------- softmax(z @ cell_k^T / 4) -> w [T,32] ----------------
__global__ __launch_bounds__(256) void memcell_w_kern(
    const float* __restrict__ z, const float* __restrict__ ck, float* __restrict__ wout)
{
    int t = blockIdx.x * 256 + threadIdx.x;
    float zv[16];
    const float4* zp = (const float4*)(z + (size_t)t * 16);
#pragma unroll
    for (int i = 0; i < 4; i++) {
        float4 v = zp[i];
        zv[4 * i] = v.x; zv[4 * i + 1] = v.y; zv[4 * i + 2] = v.z; zv[4 * i + 3] = v.w;
    }
    float lg[32]; float mx = -1e30f;
#pragma unroll
    for (int m = 0; m < 32; m++) {
        float a = 0.f;
#pragma unroll
        for (int n = 0; n < 16; n++) a += zv[n] * ck[m * 16 + n];
        a *= 0.25f;
        lg[m] = a; mx = fmaxf(mx, a);
    }
    float s = 0.f;
#pragma unroll
    for (int m = 0; m < 32; m++) { lg[m] = __expf(lg[m] - mx); s += lg[m]; }
    float inv = 1.f / s;
    float4* wp = (float4*)(wout + (size_t)t * 32);
#pragma unroll
    for (int m = 0; m < 8; m++)
        wp[m] = make_float4(lg[4 * m] * inv, lg[4 * m + 1] * inv,
                            lg[4 * m + 2] * inv, lg[4 * m + 3] * inv);
}

// ---------------- WtW = w^T w [32,32], WtT = w^T t_star [32,128] ----------------
__global__ __launch_bounds__(256) void memcell_acc_kern(
    const float* __restrict__ wmat, const float* __restrict__ tstar,
    float* __restrict__ WtW, float* __restrict__ WtT)
{
    __shared__ float ws[64][32];
    __shared__ float ts[64][128];
    int tid = threadIdx.x;
    int sg = tid & 31, mg = tid >> 5;        // WtT tile
    int mW = tid & 31, m2 = (tid >> 5) * 4;  // WtW tile
    float accT[16], accW[4];
#pragma unroll
    for (int i = 0; i < 16; i++) accT[i] = 0.f;
#pragma unroll
    for (int i = 0; i < 4; i++) accW[i] = 0.f;

    for (int c = blockIdx.x; c < 2048; c += 256) {
        size_t base = (size_t)c * 64;
        __syncthreads();
        {
            const float4* src = (const float4*)(wmat + base * 32);
            float4* dst = (float4*)&ws[0][0];
#pragma unroll
            for (int i = 0; i < 2; i++) dst[tid + 256 * i] = src[tid + 256 * i];
            const float4* src2 = (const float4*)(tstar + base * 128);
            float4* dst2 = (float4*)&ts[0][0];
#pragma unroll
            for (int i = 0; i < 8; i++) dst2[tid + 256 * i] = src2[tid + 256 * i];
        }
        __syncthreads();
        for (int t = 0; t < 64; t++) {
            float wv[4];
#pragma unroll
            for (int i = 0; i < 4; i++) wv[i] = ws[t][mg * 4 + i];
            float4 sv = *(const float4*)&ts[t][sg * 4];
#pragma unroll
            for (int i = 0; i < 4; i++) {
                accT[i * 4 + 0] += wv[i] * sv.x; accT[i * 4 + 1] += wv[i] * sv.y;
                accT[i * 4 + 2] += wv[i] * sv.z; accT[i * 4 + 3] += wv[i] * sv.w;
            }
            float wa = ws[t][mW];
            float4 wb = *(const float4*)&ws[t][m2];
            accW[0] += wa * wb.x; accW[1] += wa * wb.y;
            accW[2] += wa * wb.z; accW[3] += wa * wb.w;
        }
    }
#pragma unroll
    for (int i = 0; i < 4; i++)
#pragma unroll
        for (int j = 0; j < 4; j++)
            atomicAdd(&WtT[(mg * 4 + i) * 128 + sg * 4 + j], accT[i * 4 + j]);
#pragma unroll
    for (int j = 0; j < 4; j++)
        atomicAdd(&WtW[mW * 32 + m2 + j], accW[j]);
}

// ------- cell_v_new = cell_v + ALPHA*(WtT - WtW @ cell_v)  [32,128] -------
__global__ __launch_bounds__(256) void cvnew_kern(
    const float* __restrict__ cv, const float* __restrict__ WtW,
    const float* __restrict__ WtT, float* __restrict__ cvn)
{
    int idx = blockIdx.x * 256 + threadIdx.x;   // 4096
    int s = idx & 127, m = idx >> 7;
    float g = WtT[idx];
#pragma unroll
    for (int j = 0; j < 32; j++) g -= WtW[m * 32 + j] * cv[j * 128 + s];
    cvn[idx] = cv[idx] + ALPHA_F * g;
}

// ------- t_read = w @ cell_v_new, scattered to NCHW d0m [8,128,128,128] -------
__global__ __launch_bounds__(256) void memcell_read_kern(
    const float* __restrict__ wmat, const float* __restrict__ cvn, float* __restrict__ d0m)
{
    int t = blockIdx.x * 256 + threadIdx.x;
    int w2 = t & 127, h2 = (t >> 7) & 127, b = t >> 14;
    float wv[32];
    const float4* wp = (const float4*)(wmat + (size_t)t * 32);
#pragma unroll
    for (int i = 0; i < 8; i++) {
        float4 v = wp[i];
        wv[4 * i] = v.x; wv[4 * i + 1] = v.y; wv[4 * i + 2] = v.z; wv[4 * i + 3] = v.w;
    }
    float* ob = d0m + (size_t)b * 128 * 16384 + (h2 << 7) + w2;
    for (int s = 0; s < 128; s++) {
        float a = 0.f;
#pragma unroll
        for (int m = 0; m < 32; m++) a += wv[m] * cvn[m * 128 + s];  // uniform -> s_load
        ob[(size_t)s * 16384] = a;
    }
}

// ------- ConvTranspose2d(128->3, k4, s2, p1) + bias + silu -------
__global__ __launch_bounds__(256) void deconv_silu_kern(
    const float* __restrict__ in, const float* __restrict__ dw,
    const float* __restrict__ db, float* __restrict__ out)
{
    int idx = blockIdx.x * 256 + threadIdx.x;   // (b,h2,w2)
    int ph = blockIdx.y >> 1, pw = blockIdx.y & 1;
    int w2 = idx & 127, h2 = (idx >> 7) & 127, b = idx >> 14;
    int h = 2 * h2 + ph, w = 2 * w2 + pw;
    int ihs[2], khs[2], iws[2], kws[2];
    ihs[0] = ph ? h2     : h2 - 1;  khs[0] = ph ? 2 : 3;
    ihs[1] = ph ? h2 + 1 : h2;      khs[1] = ph ? 0 : 1;
    iws[0] = pw ? w2     : w2 - 1;  kws[0] = pw ? 2 : 3;
    iws[1] = pw ? w2 + 1 : w2;      kws[1] = pw ? 0 : 1;
    float a0 = db[0], a1 = db[1], a2 = db[2];
    const float* ib = in + (size_t)b * 128 * 16384;
#pragma unroll
    for (int i = 0; i < 2; i++) {
        if ((unsigned)ihs[i] >= 128u) continue;
#pragma unroll
        for (int j = 0; j < 2; j++) {
            if ((unsigned)iws[j] >= 128u) continue;
            const float* p = ib + (ihs[i] << 7) + iws[j];
            int wb = khs[i] * 4 + kws[j];      // uniform
            for (int ci = 0; ci < 128; ci++) {
                float v = p[(size_t)ci * 16384];
                a0 += v * dw[ci * 48 + wb];
                a1 += v * dw[ci * 48 + 16 + wb];
                a2 += v * dw[ci * 48 + 32 + wb];
            }
        }
    }
    size_t ob = (size_t)b * 3 * 65536 + ((size_t)h << 8) + w;
    out[ob]          = silu_f(a0);
    out[ob + 65536]  = silu_f(a1);
    out[ob + 131072] = silu_f(a2);
}

extern "C" void kernel_launch(void* const* d_in, const int* in_sizes, int n_in,
                              void* d_out, int out_size, void* d_ws, size_t ws_size,
                              hipStream_t stream)
{
    const float* x      = (const float*)d_in[0];
    const float* e0n_w1 = (const float*)d_in[1];
    const float* e0n_b1 = (const float*)d_in[2];
    const float* e0n_w2 = (const float*)d_in[3];
    const float* e0n_b2 = (const float*)d_in[4];
    const float* e0s_w1 = (const float*)d_in[5];
    const float* e0s_b1 = (const float*)d_in[6];
    const float* e0s_w2 = (const float*)d_in[7];
    const float* e0s_b2 = (const float*)d_in[8];
    const float* d0_dw  = (const float*)d_in[9];
    const float* d0_db  = (const float*)d_in[10];
    const float* d0_cw  = (const float*)d_in[11];
    const float* d0_cb  = (const float*)d_in[12];
    const float* cell_k = (const float*)d_in[13];
    const float* cell_v = (const float*)d_in[14];
    float* outp = (float*)d_out;

    char* ws = (char*)d_ws;
    __hip_bfloat16* a_s = (__hip_bfloat16*)(ws);
    float* t_star = (float*)(ws + 134217728);
    float* a_n    = (float*)(ws + 201326592);
    __hip_bfloat16* wt2 = (__hip_bfloat16*)(ws + 201326592);  // reuses a_n after conv2_n
    float* z      = (float*)(ws + 234881024);
    float* wmat   = (float*)(ws + 243269632);
    float* WtW    = (float*)(ws + 260046848);
    float* WtT    = (float*)(ws + 260050944);
    float* cvn    = (float*)(ws + 260067328);
    float* d0m    = (float*)(ws);               // reuse a_s region
    float* dec1   = (float*)(ws + 67108864);    // reuse a_s region (tail)

    // n-branch encoder (a_n dead after conv2s2_silu)
    conv1_silu<16><<<2048, 256, 0, stream>>>(x, e0n_w1, e0n_b1, a_n);
    conv2s2_silu<16, 16><<<512, 256, 0, stream>>>(a_n, e0n_w2, e0n_b2, z);
    // s-branch encoder: NC8HW8 conv1 -> MFMA implicit-GEMM conv2
    wprep_kern<<<576, 256, 0, stream>>>(e0s_w2, wt2);
    conv1s_nhwc<<<2048, 256, 0, stream>>>(x, e0s_w1, e0s_b1, a_s);
    conv2s_mfma<<<2048, 256, 0, stream>>>(a_s, wt2, e0s_b2, t_star);
    // memcell
    memcell_w_kern<<<512, 256, 0, stream>>>(z, cell_k, wmat);
    hipMemsetAsync(WtW, 0, (1024 + 4096) * sizeof(float), stream);
    memcell_acc_kern<<<256, 256, 0, stream>>>(wmat, t_star, WtW, WtT);
    cvnew_kern<<<16, 256, 0, stream>>>(cell_v, WtW, WtT, cvn);
    memcell_read_kern<<<512, 256, 0, stream>>>(wmat, cvn, d0m);
    // decoder
    dim3 dg(512, 4);
    deconv_silu_kern<<<dg, 256, 0, stream>>>(d0m, d0_dw, d0_db, dec1);
    conv1_silu<3><<<2048, 256, 0, stream>>>(dec1, d0_cw, d0_cb, outp);
}

// Round 4
// 517.807 us; speedup vs baseline: 4.4883x; 1.1017x over previous
//
#include <hip/hip_runtime.h>
#include <hip/hip_bf16.h>

// CPSFMemcellAutoencoder: B=8, 256x256 input, N=16, S=128, M=32, T=131072.
// Workspace layout (~260 MB):
//   [0, 134217728)            a_s   : NC8HW8 [8][16 cig][65536 hw][8 ci] bf16 (s-branch conv1 out)
//   [134217728, 201326592)    t_star: [T,128] f32 token-major
//   [201326592, 234881024)    a_n   : [8,16,256,256] f32; REUSED for Wt[9][128][128] bf16 after conv2_n
//   [234881024, 243269632)    z     : [T,16] f32
//   [243269632, 260046848)    wmat  : [T,32] f32
//   [260046848, 260050944)    WtW   : [32,32] f32
//   [260050944, 260067328)    WtT   : [32,128] f32
//   [260067328, 260083712)    cvn   : [32,128] f32
//   d0m  reuses [0, 67108864)        : [8,128,128,128] f32
//   dec1 reuses [67108864, 73400320) : [8,3,256,256] f32

#define ALPHA_F 1e-6f

typedef __attribute__((ext_vector_type(8))) short bf16x8;
typedef __attribute__((ext_vector_type(4))) float f32x4;

__device__ __forceinline__ float silu_f(float x) {
    return x / (1.f + __expf(-x));
}

// ---------------- conv 3x3, Cin=3, stride 1, pad 1, + bias + silu (NCHW f32 out) ----------------
template<int CO>
__global__ __launch_bounds__(256) void conv1_silu(
    const float* __restrict__ x, const float* __restrict__ wgt,
    const float* __restrict__ bias, float* __restrict__ out)
{
    int idx = blockIdx.x * 256 + threadIdx.x;      // (b,h,w)
    int w = idx & 255, h = (idx >> 8) & 255, b = idx >> 16;
    const float* xb = x + (size_t)b * 3 * 65536;
    float in[27];
#pragma unroll
    for (int ci = 0; ci < 3; ci++)
#pragma unroll
        for (int ky = 0; ky < 3; ky++)
#pragma unroll
            for (int kx = 0; kx < 3; kx++) {
                int hh = h + ky - 1, ww = w + kx - 1;
                bool ok = ((unsigned)hh < 256u) && ((unsigned)ww < 256u);
                in[(ci * 3 + ky) * 3 + kx] = ok ? xb[(ci << 16) + (hh << 8) + ww] : 0.f;
            }
    float* ob = out + (size_t)b * CO * 65536 + (h << 8) + w;
#pragma unroll 4
    for (int co = 0; co < CO; co++) {
        float acc = bias[co];          // uniform index -> s_load
#pragma unroll
        for (int k = 0; k < 27; k++) acc += in[k] * wgt[co * 27 + k];
        ob[(size_t)co << 16] = silu_f(acc);
    }
}

// ---------------- s-branch conv1: 3->128, NC8HW8 bf16 output ----------------
__global__ __launch_bounds__(256) void conv1s_nhwc(
    const float* __restrict__ x, const float* __restrict__ wgt,
    const float* __restrict__ bias, __hip_bfloat16* __restrict__ out)
{
    int idx = blockIdx.x * 256 + threadIdx.x;      // (b,h,w)
    int w = idx & 255, h = (idx >> 8) & 255, b = idx >> 16;
    int hw = (h << 8) + w;
    const float* xb = x + (size_t)b * 3 * 65536;
    float in[27];
#pragma unroll
    for (int ci = 0; ci < 3; ci++)
#pragma unroll
        for (int ky = 0; ky < 3; ky++)
#pragma unroll
            for (int kx = 0; kx < 3; kx++) {
                int hh = h + ky - 1, ww = w + kx - 1;
                bool ok = ((unsigned)hh < 256u) && ((unsigned)ww < 256u);
                in[(ci * 3 + ky) * 3 + kx] = ok ? xb[(ci << 16) + (hh << 8) + ww] : 0.f;
            }
    float4* ob = (float4*)out + (size_t)b * 16 * 65536 + hw;
#pragma unroll
    for (int j = 0; j < 16; j++) {
        union { __hip_bfloat16 hh[8]; float4 v; } u;
#pragma unroll
        for (int u8 = 0; u8 < 8; u8++) {
            int co = j * 8 + u8;
            float acc = bias[co];
#pragma unroll
            for (int k = 0; k < 27; k++) acc += in[k] * wgt[co * 27 + k];
            u.hh[u8] = __float2bfloat16(silu_f(acc));
        }
        ob[(size_t)j * 65536] = u.v;
    }
}

// ---------------- weight prep: Wt[pos][co][ci] bf16 from W[co][ci][ky][kx] f32 ----------------
__global__ __launch_bounds__(256) void wprep_kern(
    const float* __restrict__ w, __hip_bfloat16* __restrict__ wt)
{
    int i = blockIdx.x * 256 + threadIdx.x;        // 147456
    int pos = i >> 14, rem = i & 16383;
    int co = rem >> 7, ci = rem & 127;
    wt[i] = __float2bfloat16(w[co * 1152 + ci * 9 + pos]);
}

// ------------- conv2_s as implicit GEMM: M=T x N=128co x K=1152, bf16 MFMA -------------
#define LDSK 40   // padded k-stride (bf16 elems): 80B rows -> only 2-way bank aliasing (free)
__global__ __launch_bounds__(256) void conv2s_mfma(
    const __hip_bfloat16* __restrict__ a_s,   // NC8HW8 [8][16][65536][8]
    const __hip_bfloat16* __restrict__ wt,    // [9][128co][128ci]
    const float* __restrict__ bias, float* __restrict__ out)  // [T][128]
{
    __shared__ __align__(16) short As[64 * LDSK];
    __shared__ __align__(16) short Bs[128 * LDSK];
    int tid = threadIdx.x;
    int g = blockIdx.x;                 // 2048 tiles
    int b = g >> 8, h2 = (g >> 1) & 127, w2base = (g & 1) * 64;
    int lane = tid & 63, wave = tid >> 6;

    int tokA = tid >> 2, cqA = tid & 3;         // A staging: token, ci8-group
    int w2A = w2base + tokA;
    int mrow = lane & 15, koff8 = (lane >> 4) * 8;

    f32x4 acc[2][4];
#pragma unroll
    for (int i = 0; i < 2; i++)
#pragma unroll
        for (int j = 0; j < 4; j++)
#pragma unroll
            for (int r = 0; r < 4; r++) acc[i][j][r] = 0.f;

    const float4* ab8 = (const float4*)a_s + (size_t)b * 16 * 65536;

    for (int pos = 0; pos < 9; pos++) {
        int ky = pos / 3, kx = pos - 3 * ky;    // uniform
        int y = 2 * h2 - 1 + ky;
        int x = 2 * w2A - 1 + kx;
        bool okA = ((unsigned)y < 256u) && ((unsigned)x < 256u);
        int pix = (y << 8) + x;
        const __hip_bfloat16* wp = wt + (size_t)pos * 16384;
#pragma unroll 1
        for (int cc = 0; cc < 4; cc++) {        // ci chunks of 32
            float4 av = make_float4(0.f, 0.f, 0.f, 0.f);
            if (okA) av = ab8[(size_t)(cc * 4 + cqA) * 65536 + pix];
            int c1 = tid + 256;
            float4 b0 = *(const float4*)(wp + (size_t)(tid >> 2) * 128 + cc * 32 + (tid & 3) * 8);
            float4 b1 = *(const float4*)(wp + (size_t)(c1 >> 2) * 128 + cc * 32 + (c1 & 3) * 8);
            __syncthreads();                    // previous iter's LDS reads done
            *(float4*)&As[tokA * LDSK + cqA * 8] = av;
            *(float4*)&Bs[(tid >> 2) * LDSK + (tid & 3) * 8] = b0;
            *(float4*)&Bs[(c1 >> 2) * LDSK + (c1 & 3) * 8] = b1;
            __syncthreads();
            bf16x8 bfr[2], afr[4];
#pragma unroll
            for (int nt = 0; nt < 2; nt++)
                bfr[nt] = *(bf16x8*)&Bs[(wave * 32 + nt * 16 + mrow) * LDSK + koff8];
#pragma unroll
            for (int mt = 0; mt < 4; mt++)
                afr[mt] = *(bf16x8*)&As[(mt * 16 + mrow) * LDSK + koff8];
#pragma unroll
            for (int nt = 0; nt < 2; nt++)
#pragma unroll
                for (int mt = 0; mt < 4; mt++)
                    acc[nt][mt] = __builtin_amdgcn_mfma_f32_16x16x32_bf16(
                        afr[mt], bfr[nt], acc[nt][mt], 0, 0, 0);
        }
    }
    // epilogue: D[row=m=(lane>>4)*4+r][col=n=lane&15]
    int rowg = (lane >> 4) * 4;
    size_t tbase = (size_t)g * 64;
#pragma unroll
    for (int nt = 0; nt < 2; nt++) {
        int co = wave * 32 + nt * 16 + (lane & 15);
        float bv = bias[co];
#pragma unroll
        for (int mt = 0; mt < 4; mt++)
#pragma unroll
            for (int r = 0; r < 4; r++) {
                int m = mt * 16 + rowg + r;
                out[(tbase + m) * 128 + co] = silu_f(acc[nt][mt][r] + bv);
            }
    }
}

// ------------- conv 3x3, stride 2, pad 1, + bias + silu, token-major out (n-branch) -------------
template<int CI, int CO>
__global__ __launch_bounds__(256) void conv2s2_silu(
    const float* __restrict__ in, const float* __restrict__ wgt,
    const float* __restrict__ bias, float* __restrict__ out)
{
    int idx = blockIdx.x * 256 + threadIdx.x;      // token (b,h2,w2)
    int w2 = idx & 127, h2 = (idx >> 7) & 127, b = idx >> 14;
    const float* ib = in + (size_t)b * CI * 65536;
    float acc[CO];
#pragma unroll
    for (int co = 0; co < CO; co++) acc[co] = bias[co];
    int h0 = 2 * h2 - 1, w0 = 2 * w2 - 1;
    for (int ci = 0; ci < CI; ci++) {
        float t[9];
#pragma unroll
        for (int ky = 0; ky < 3; ky++)
#pragma unroll
            for (int kx = 0; kx < 3; kx++) {
                int hh = h0 + ky, ww = w0 + kx;
                bool ok = ((unsigned)hh < 256u) && ((unsigned)ww < 256u);
                t[ky * 3 + kx] = ok ? ib[((size_t)ci << 16) + (hh << 8) + ww] : 0.f;
            }
#pragma unroll
        for (int co = 0; co < CO; co++)
#pragma unroll
            for (int k = 0; k < 9; k++)
                acc[co] += t[k] * wgt[(co * CI + ci) * 9 + k];   // uniform -> s_load
    }
    float* ob = out + (size_t)idx * CO;
#pragma unroll
    for (int co = 0; co < CO; co++) ob[co] = silu_f(acc[co]);
}

// ---------------- softmax(z @ cell_k^T / 4) -> w [T,32] ----------------
__global__ __launch_bounds__(256) void memcell_w_kern(
    const float* __restrict__ z, const float* __restrict__ ck, float* __restrict__ wout)
{
    int t = blockIdx.x * 256 + threadIdx.x;
    float zv[16];
    const float4* zp = (const float4*)(z + (size_t)t * 16);
#pragma unroll
    for (int i = 0; i < 4; i++) {
        float4 v = zp[i];
        zv[4 * i] = v.x; zv[4 * i + 1] = v.y; zv[4 * i + 2] = v.z; zv[4 * i + 3] = v.w;
    }
    float lg[32]; float mx = -1e30f;
#pragma unroll
    for (int m = 0; m < 32; m++) {
        float a = 0.f;
#pragma unroll
        for (int n = 0; n < 16; n++) a += zv[n] * ck[m * 16 + n];
        a *= 0.25f;
        lg[m] = a; mx = fmaxf(mx, a);
    }
    float s = 0.f;
#pragma unroll
    for (int m = 0; m < 32; m++) { lg[m] = __expf(lg[m] - mx); s += lg[m]; }
    float inv = 1.f / s;
    float4* wp = (float4*)(wout + (size_t)t * 32);
#pragma unroll
    for (int m = 0; m < 8; m++)
        wp[m] = make_float4(lg[4 * m] * inv, lg[4 * m + 1] * inv,
                            lg[4 * m + 2] * inv, lg[4 * m + 3] * inv);
}

// ---------------- WtW = w^T w [32,32], WtT = w^T t_star [32,128] ----------------
__global__ __launch_bounds__(256) void memcell_acc_kern(
    const float* __restrict__ wmat, const float* __restrict__ tstar,
    float* __restrict__ WtW, float* __restrict__ WtT)
{
    __shared__ float ws[64][32];
    __shared__ float ts[64][128];
    int tid = threadIdx.x;
    int sg = tid & 31, mg = tid >> 5;        // WtT tile
    int mW = tid & 31, m2 = (tid >> 5) * 4;  // WtW tile
    float accT[16], accW[4];
#pragma unroll
    for (int i = 0; i < 16; i++) accT[i] = 0.f;
#pragma unroll
    for (int i = 0; i < 4; i++) accW[i] = 0.f;

    for (int c = blockIdx.x; c < 2048; c += 256) {
        size_t base = (size_t)c * 64;
        __syncthreads();
        {
            const float4* src = (const float4*)(wmat + base * 32);
            float4* dst = (float4*)&ws[0][0];
#pragma unroll
            for (int i = 0; i < 2; i++) dst[tid + 256 * i] = src[tid + 256 * i];
            const float4* src2 = (const float4*)(tstar + base * 128);
            float4* dst2 = (float4*)&ts[0][0];
#pragma unroll
            for (int i = 0; i < 8; i++) dst2[tid + 256 * i] = src2[tid + 256 * i];
        }
        __syncthreads();
        for (int t = 0; t < 64; t++) {
            float wv[4];
#pragma unroll
            for (int i = 0; i < 4; i++) wv[i] = ws[t][mg * 4 + i];
            float4 sv = *(const float4*)&ts[t][sg * 4];
#pragma unroll
            for (int i = 0; i < 4; i++) {
                accT[i * 4 + 0] += wv[i] * sv.x; accT[i * 4 + 1] += wv[i] * sv.y;
                accT[i * 4 + 2] += wv[i] * sv.z; accT[i * 4 + 3] += wv[i] * sv.w;
            }
            float wa = ws[t][mW];
            float4 wb = *(const float4*)&ws[t][m2];
            accW[0] += wa * wb.x; accW[1] += wa * wb.y;
            accW[2] += wa * wb.z; accW[3] += wa * wb.w;
        }
    }
#pragma unroll
    for (int i = 0; i < 4; i++)
#pragma unroll
        for (int j = 0; j < 4; j++)
            atomicAdd(&WtT[(mg * 4 + i) * 128 + sg * 4 + j], accT[i * 4 + j]);
#pragma unroll
    for (int j = 0; j < 4; j++)
        atomicAdd(&WtW[mW * 32 + m2 + j], accW[j]);
}

// ------- cell_v_new = cell_v + ALPHA*(WtT - WtW @ cell_v)  [32,128] -------
__global__ __launch_bounds__(256) void cvnew_kern(
    const float* __restrict__ cv, const float* __restrict__ WtW,
    const float* __restrict__ WtT, float* __restrict__ cvn)
{
    int idx = blockIdx.x * 256 + threadIdx.x;   // 4096
    int s = idx & 127, m = idx >> 7;
    float g = WtT[idx];
#pragma unroll
    for (int j = 0; j < 32; j++) g -= WtW[m * 32 + j] * cv[j * 128 + s];
    cvn[idx] = cv[idx] + ALPHA_F * g;
}

// ------- t_read = w @ cell_v_new, scattered to NCHW d0m [8,128,128,128] -------
__global__ __launch_bounds__(256) void memcell_read_kern(
    const float* __restrict__ wmat, const float* __restrict__ cvn, float* __restrict__ d0m)
{
    int t = blockIdx.x * 256 + threadIdx.x;
    int w2 = t & 127, h2 = (t >> 7) & 127, b = t >> 14;
    float wv[32];
    const float4* wp = (const float4*)(wmat + (size_t)t * 32);
#pragma unroll
    for (int i = 0; i < 8; i++) {
        float4 v = wp[i];
        wv[4 * i] = v.x; wv[4 * i + 1] = v.y; wv[4 * i + 2] = v.z; wv[4 * i + 3] = v.w;
    }
    float* ob = d0m + (size_t)b * 128 * 16384 + (h2 << 7) + w2;
    for (int s = 0; s < 128; s++) {
        float a = 0.f;
#pragma unroll
        for (int m = 0; m < 32; m++) a += wv[m] * cvn[m * 128 + s];  // uniform -> s_load
        ob[(size_t)s * 16384] = a;
    }
}

// ------- ConvTranspose2d(128->3, k4, s2, p1) + bias + silu, all 4 parities/thread -------
// Each thread: one token (b,h2,w2) -> 2x2 output pixels, reads 3x3 input taps once.
// Blocks tile 16x16 tokens for halo reuse (18/16)^2 ~= 1.27x fetch amplification.
// Row/col tap->output maps (a = ih-(h2-1), bb = iw-(w2-1)):
//   a=0: (ph=0,kh=3); a=1: (ph=0,kh=1),(ph=1,kh=2); a=2: (ph=1,kh=0)   (same for cols)
__global__ __launch_bounds__(256) void deconv_silu_kern(
    const float* __restrict__ in, const float* __restrict__ dw,
    const float* __restrict__ db, float* __restrict__ out)
{
    int g = blockIdx.x;                   // 512: b*64 + hb*8 + wb
    int wb = g & 7, hb = (g >> 3) & 7, b = g >> 6;
    int tx = threadIdx.x & 15, ty = threadIdx.x >> 4;
    int h2 = hb * 16 + ty, w2 = wb * 16 + tx;

    float mh[3], mw[3];
    int ihc[3], iwc[3];
#pragma unroll
    for (int a = 0; a < 3; a++) {
        int v = h2 - 1 + a;
        mh[a] = ((unsigned)v < 128u) ? 1.f : 0.f;
        ihc[a] = v < 0 ? 0 : (v > 127 ? 127 : v);
        v = w2 - 1 + a;
        mw[a] = ((unsigned)v < 128u) ? 1.f : 0.f;
        iwc[a] = v < 0 ? 0 : (v > 127 ? 127 : v);
    }
    const float* base = in + (size_t)b * 128 * 16384;
    const float* p[3][3];
    float msk[3][3];
#pragma unroll
    for (int a = 0; a < 3; a++)
#pragma unroll
        for (int c = 0; c < 3; c++) {
            p[a][c] = base + (ihc[a] << 7) + iwc[c];
            msk[a][c] = mh[a] * mw[c];
        }

    float acc[2][2][3];
#pragma unroll
    for (int ph = 0; ph < 2; ph++)
#pragma unroll
        for (int pw = 0; pw < 2; pw++)
#pragma unroll
            for (int co = 0; co < 3; co++) acc[ph][pw][co] = db[co];

    // tap->output maps
    const int RA[4] = {0, 1, 1, 2}, RP[4] = {0, 0, 1, 1}, RK[4] = {3, 1, 2, 0};

    for (int ci = 0; ci < 128; ci++) {
        float t[3][3];
#pragma unroll
        for (int a = 0; a < 3; a++)
#pragma unroll
            for (int c = 0; c < 3; c++)
                t[a][c] = msk[a][c] * p[a][c][(size_t)ci << 14];
        const float* wc = dw + ci * 48;     // [co][kh][kw], uniform -> s_load
#pragma unroll
        for (int ri = 0; ri < 4; ri++)
#pragma unroll
            for (int cj = 0; cj < 4; cj++) {
                float tv = t[RA[ri]][RA[cj]];
                int ph = RP[ri], pw = RP[cj];
                int widx = RK[ri] * 4 + RK[cj];
#pragma unroll
                for (int co = 0; co < 3; co++)
                    acc[ph][pw][co] += tv * wc[co * 16 + widx];
            }
    }
    int h = 2 * h2, w = 2 * w2;
#pragma unroll
    for (int ph = 0; ph < 2; ph++)
#pragma unroll
        for (int co = 0; co < 3; co++) {
            float2 v = make_float2(silu_f(acc[ph][0][co]), silu_f(acc[ph][1][co]));
            *(float2*)&out[(size_t)b * 3 * 65536 + (size_t)co * 65536 + ((size_t)(h + ph) << 8) + w] = v;
        }
}

extern "C" void kernel_launch(void* const* d_in, const int* in_sizes, int n_in,
                              void* d_out, int out_size, void* d_ws, size_t ws_size,
                              hipStream_t stream)
{
    const float* x      = (const float*)d_in[0];
    const float* e0n_w1 = (const float*)d_in[1];
    const float* e0n_b1 = (const float*)d_in[2];
    const float* e0n_w2 = (const float*)d_in[3];
    const float* e0n_b2 = (const float*)d_in[4];
    const float* e0s_w1 = (const float*)d_in[5];
    const float* e0s_b1 = (const float*)d_in[6];
    const float* e0s_w2 = (const float*)d_in[7];
    const float* e0s_b2 = (const float*)d_in[8];
    const float* d0_dw  = (const float*)d_in[9];
    const float* d0_db  = (const float*)d_in[10];
    const float* d0_cw  = (const float*)d_in[11];
    const float* d0_cb  = (const float*)d_in[12];
    const float* cell_k = (const float*)d_in[13];
    const float* cell_v = (const float*)d_in[14];
    float* outp = (float*)d_out;

    char* ws = (char*)d_ws;
    __hip_bfloat16* a_s = (__hip_bfloat16*)(ws);
    float* t_star = (float*)(ws + 134217728);
    float* a_n    = (float*)(ws + 201326592);
    __hip_bfloat16* wt2 = (__hip_bfloat16*)(ws + 201326592);  // reuses a_n after conv2_n
    float* z      = (float*)(ws + 234881024);
    float* wmat   = (float*)(ws + 243269632);
    float* WtW    = (float*)(ws + 260046848);
    float* WtT    = (float*)(ws + 260050944);
    float* cvn    = (float*)(ws + 260067328);
    float* d0m    = (float*)(ws);               // reuse a_s region
    float* dec1   = (float*)(ws + 67108864);    // reuse a_s region (tail)

    // n-branch encoder (a_n dead after conv2s2_silu)
    conv1_silu<16><<<2048, 256, 0, stream>>>(x, e0n_w1, e0n_b1, a_n);
    conv2s2_silu<16, 16><<<512, 256, 0, stream>>>(a_n, e0n_w2, e0n_b2, z);
    // s-branch encoder: NC8HW8 conv1 -> MFMA implicit-GEMM conv2
    wprep_kern<<<576, 256, 0, stream>>>(e0s_w2, wt2);
    conv1s_nhwc<<<2048, 256, 0, stream>>>(x, e0s_w1, e0s_b1, a_s);
    conv2s_mfma<<<2048, 256, 0, stream>>>(a_s, wt2, e0s_b2, t_star);
    // memcell
    memcell_w_kern<<<512, 256, 0, stream>>>(z, cell_k, wmat);
    hipMemsetAsync(WtW, 0, (1024 + 4096) * sizeof(float), stream);
    memcell_acc_kern<<<256, 256, 0, stream>>>(wmat, t_star, WtW, WtT);
    cvnew_kern<<<16, 256, 0, stream>>>(cell_v, WtW, WtT, cvn);
    memcell_read_kern<<<512, 256, 0, stream>>>(wmat, cvn, d0m);
    // decoder
    deconv_silu_kern<<<512, 256, 0, stream>>>(d0m, d0_dw, d0_db, dec1);
    conv1_silu<3><<<2048, 256, 0, stream>>>(dec1, d0_cw, d0_cb, outp);
}

// Round 5
// 473.624 us; speedup vs baseline: 4.9070x; 1.0933x over previous
//
#include <hip/hip_runtime.h>
#include <hip/hip_bf16.h>

// CPSFMemcellAutoencoder: B=8, 256x256 input, N=16, S=128, M=32, T=131072.
// Workspace layout (~260 MB):
//   [0, 134217728)            a_s   : NC8HW8 [8][16 cig][65536 hw][8 ci] bf16 (s-branch conv1 out)
//   [134217728, 201326592)    t_star: [T,128] f32 token-major
//   [201326592, 234881024)    a_n   : [8,16,256,256] f32; REUSED for Wt[9][128][128] bf16 after conv2_n
//   [234881024, 243269632)    z     : [T,16] f32
//   [243269632, 260046848)    wmat  : [T,32] f32
//   [260046848, 260050944)    WtW   : [32,32] f32
//   [260050944, 260067328)    WtT   : [32,128] f32
//   [260067328, 260083712)    cvn   : [32,128] f32
//   d0m  reuses [0, 67108864)        : [8,128,128,128] f32
//   dec1 reuses [67108864, 73400320) : [8,3,256,256] f32

#define ALPHA_F 1e-6f

typedef __attribute__((ext_vector_type(8))) short bf16x8;
typedef __attribute__((ext_vector_type(4))) float f32x4;

__device__ __forceinline__ float silu_f(float x) {
    return x / (1.f + __expf(-x));
}

__device__ __forceinline__ short f2bf(float f) {
    __hip_bfloat16 h = __float2bfloat16(f);
    union { __hip_bfloat16 b; short s; } u; u.b = h; return u.s;
}

// ---------------- conv 3x3, Cin=3, stride 1, pad 1, + bias + silu (NCHW f32 out) ----------------
template<int CO>
__global__ __launch_bounds__(256) void conv1_silu(
    const float* __restrict__ x, const float* __restrict__ wgt,
    const float* __restrict__ bias, float* __restrict__ out)
{
    int idx = blockIdx.x * 256 + threadIdx.x;      // (b,h,w)
    int w = idx & 255, h = (idx >> 8) & 255, b = idx >> 16;
    const float* xb = x + (size_t)b * 3 * 65536;
    float in[27];
#pragma unroll
    for (int ci = 0; ci < 3; ci++)
#pragma unroll
        for (int ky = 0; ky < 3; ky++)
#pragma unroll
            for (int kx = 0; kx < 3; kx++) {
                int hh = h + ky - 1, ww = w + kx - 1;
                bool ok = ((unsigned)hh < 256u) && ((unsigned)ww < 256u);
                in[(ci * 3 + ky) * 3 + kx] = ok ? xb[(ci << 16) + (hh << 8) + ww] : 0.f;
            }
    float* ob = out + (size_t)b * CO * 65536 + (h << 8) + w;
#pragma unroll 4
    for (int co = 0; co < CO; co++) {
        float acc = bias[co];          // uniform index -> s_load
#pragma unroll
        for (int k = 0; k < 27; k++) acc += in[k] * wgt[co * 27 + k];
        ob[(size_t)co << 16] = silu_f(acc);
    }
}

// ---------------- s-branch conv1 as single-K-step MFMA GEMM ----------------
// M=128 co (A=weights), N=128 pixels (B=im2col), K=27 padded to 32, bf16.
// Block = half an image row (128 consecutive w). Epilogue: lane holds 4
// consecutive co for one pixel -> bf16x4 store; wave store covers two fully-
// populated 256B segments of NC8HW8. Weights (13.8KB) stay L2-resident.
#define C1K 40   // padded k-stride (shorts); 80B rows (mult of 16B, 2-way bank alias only)
__global__ __launch_bounds__(256) void conv1s_mfma(
    const float* __restrict__ x, const float* __restrict__ wgt,
    const float* __restrict__ bias, __hip_bfloat16* __restrict__ out)
{
    __shared__ __align__(16) short Ps[128 * C1K];  // [pixel][k]
    __shared__ __align__(16) short Ws[128 * C1K];  // [co][k]
    int tid = threadIdx.x;
    int g = blockIdx.x;                 // 4096: b*512 + rem
    int b = g >> 9, rem = g & 511;
    int h = rem >> 1, w0 = (rem & 1) * 128;

    // ---- staging: waves 0-1 build im2col rows, waves 2-3 stage weights ----
    union { short s[32]; float4 v4[4]; } row;
#pragma unroll
    for (int k = 0; k < 32; k++) row.s[k] = 0;
    if (tid < 128) {
        int wpix = w0 + tid;
        const float* xb = x + (size_t)b * 3 * 65536;
#pragma unroll
        for (int ci = 0; ci < 3; ci++)
#pragma unroll
            for (int ky = 0; ky < 3; ky++)
#pragma unroll
                for (int kx = 0; kx < 3; kx++) {
                    int hh = h + ky - 1, ww = wpix + kx - 1;
                    float v = 0.f;
                    if (((unsigned)hh < 256u) && ((unsigned)ww < 256u))
                        v = xb[(ci << 16) + (hh << 8) + ww];
                    row.s[ci * 9 + ky * 3 + kx] = f2bf(v);
                }
#pragma unroll
        for (int j = 0; j < 4; j++) *(float4*)&Ps[tid * C1K + j * 8] = row.v4[j];
    } else {
        int co = tid - 128;
#pragma unroll
        for (int k = 0; k < 27; k++) row.s[k] = f2bf(wgt[co * 27 + k]);
#pragma unroll
        for (int j = 0; j < 4; j++) *(float4*)&Ws[co * C1K + j * 8] = row.v4[j];
    }
    __syncthreads();

    int lane = tid & 63, wave = tid >> 6;
    int coH = (wave & 1) * 64, pxH = (wave >> 1) * 64;
    int r16 = lane & 15, koff = (lane >> 4) * 8;
    bf16x8 af[4], bfr[4];
#pragma unroll
    for (int mt = 0; mt < 4; mt++)
        af[mt] = *(bf16x8*)&Ws[(coH + mt * 16 + r16) * C1K + koff];
#pragma unroll
    for (int nt = 0; nt < 4; nt++)
        bfr[nt] = *(bf16x8*)&Ps[(pxH + nt * 16 + r16) * C1K + koff];
    f32x4 acc[4][4];
#pragma unroll
    for (int mt = 0; mt < 4; mt++)
#pragma unroll
        for (int nt = 0; nt < 4; nt++) {
#pragma unroll
            for (int r = 0; r < 4; r++) acc[mt][nt][r] = 0.f;
            acc[mt][nt] = __builtin_amdgcn_mfma_f32_16x16x32_bf16(
                af[mt], bfr[nt], acc[mt][nt], 0, 0, 0);
        }

    // ---- epilogue: D[row=co=(lane>>4)*4+r (+tile)][col=pixel=lane&15 (+tile)] ----
    __hip_bfloat16* ob = out + (size_t)b * 16 * 65536 * 8;
#pragma unroll
    for (int mt = 0; mt < 4; mt++) {
        int cb = coH + mt * 16 + (lane >> 4) * 4;   // 4 consecutive co, cb%4==0
        float4 bv = *(const float4*)&bias[cb];
        float bvals[4] = {bv.x, bv.y, bv.z, bv.w};
        int cig = cb >> 3, cof = cb & 7;
#pragma unroll
        for (int nt = 0; nt < 4; nt++) {
            int p = pxH + nt * 16 + r16;
            int hw = (h << 8) + w0 + p;
            union { short s[4]; float2 v; } u;
#pragma unroll
            for (int r = 0; r < 4; r++)
                u.s[r] = f2bf(silu_f(acc[mt][nt][r] + bvals[r]));
            *(float2*)&ob[((size_t)cig * 65536 + hw) * 8 + cof] = u.v;
        }
    }
}

// ---------------- weight prep: Wt[pos][co][ci] bf16 from W[co][ci][ky][kx] f32 ----------------
__global__ __launch_bounds__(256) void wprep_kern(
    const float* __restrict__ w, __hip_bfloat16* __restrict__ wt)
{
    int i = blockIdx.x * 256 + threadIdx.x;        // 147456
    int pos = i >> 14, rem = i & 16383;
    int co = rem >> 7, ci = rem & 127;
    wt[i] = __float2bfloat16(w[co * 1152 + ci * 9 + pos]);
}

// ------------- conv2_s as implicit GEMM: M=T x N=128co x K=1152, bf16 MFMA -------------
#define LDSK 40   // padded k-stride (bf16 elems): 80B rows -> only 2-way bank aliasing (free)
__global__ __launch_bounds__(256) void conv2s_mfma(
    const __hip_bfloat16* __restrict__ a_s,   // NC8HW8 [8][16][65536][8]
    const __hip_bfloat16* __restrict__ wt,    // [9][128co][128ci]
    const float* __restrict__ bias, float* __restrict__ out)  // [T][128]
{
    __shared__ __align__(16) short As[64 * LDSK];
    __shared__ __align__(16) short Bs[128 * LDSK];
    int tid = threadIdx.x;
    int g = blockIdx.x;                 // 2048 tiles
    int b = g >> 8, h2 = (g >> 1) & 127, w2base = (g & 1) * 64;
    int lane = tid & 63, wave = tid >> 6;

    int tokA = tid >> 2, cqA = tid & 3;         // A staging: token, ci8-group
    int w2A = w2base + tokA;
    int mrow = lane & 15, koff8 = (lane >> 4) * 8;

    f32x4 acc[2][4];
#pragma unroll
    for (int i = 0; i < 2; i++)
#pragma unroll
        for (int j = 0; j < 4; j++)
#pragma unroll
            for (int r = 0; r < 4; r++) acc[i][j][r] = 0.f;

    const float4* ab8 = (const float4*)a_s + (size_t)b * 16 * 65536;

    for (int pos = 0; pos < 9; pos++) {
        int ky = pos / 3, kx = pos - 3 * ky;    // uniform
        int y = 2 * h2 - 1 + ky;
        int x = 2 * w2A - 1 + kx;
        bool okA = ((unsigned)y < 256u) && ((unsigned)x < 256u);
        int pix = (y << 8) + x;
        const __hip_bfloat16* wp = wt + (size_t)pos * 16384;
#pragma unroll 1
        for (int cc = 0; cc < 4; cc++) {        // ci chunks of 32
            float4 av = make_float4(0.f, 0.f, 0.f, 0.f);
            if (okA) av = ab8[(size_t)(cc * 4 + cqA) * 65536 + pix];
            int c1 = tid + 256;
            float4 b0 = *(const float4*)(wp + (size_t)(tid >> 2) * 128 + cc * 32 + (tid & 3) * 8);
            float4 b1 = *(const float4*)(wp + (size_t)(c1 >> 2) * 128 + cc * 32 + (c1 & 3) * 8);
            __syncthreads();                    // previous iter's LDS reads done
            *(float4*)&As[tokA * LDSK + cqA * 8] = av;
            *(float4*)&Bs[(tid >> 2) * LDSK + (tid & 3) * 8] = b0;
            *(float4*)&Bs[(c1 >> 2) * LDSK + (c1 & 3) * 8] = b1;
            __syncthreads();
            bf16x8 bfr[2], afr[4];
#pragma unroll
            for (int nt = 0; nt < 2; nt++)
                bfr[nt] = *(bf16x8*)&Bs[(wave * 32 + nt * 16 + mrow) * LDSK + koff8];
#pragma unroll
            for (int mt = 0; mt < 4; mt++)
                afr[mt] = *(bf16x8*)&As[(mt * 16 + mrow) * LDSK + koff8];
#pragma unroll
            for (int nt = 0; nt < 2; nt++)
#pragma unroll
                for (int mt = 0; mt < 4; mt++)
                    acc[nt][mt] = __builtin_amdgcn_mfma_f32_16x16x32_bf16(
                        afr[mt], bfr[nt], acc[nt][mt], 0, 0, 0);
        }
    }
    // epilogue: D[row=m=(lane>>4)*4+r][col=n=lane&15]
    int rowg = (lane >> 4) * 4;
    size_t tbase = (size_t)g * 64;
#pragma unroll
    for (int nt = 0; nt < 2; nt++) {
        int co = wave * 32 + nt * 16 + (lane & 15);
        float bv = bias[co];
#pragma unroll
        for (int mt = 0; mt < 4; mt++)
#pragma unroll
            for (int r = 0; r < 4; r++) {
                int m = mt * 16 + rowg + r;
                out[(tbase + m) * 128 + co] = silu_f(acc[nt][mt][r] + bv);
            }
    }
}

// ------------- conv 3x3, stride 2, pad 1, + bias + silu, token-major out (n-branch) -------------
template<int CI, int CO>
__global__ __launch_bounds__(256) void conv2s2_silu(
    const float* __restrict__ in, const float* __restrict__ wgt,
    const float* __restrict__ bias, float* __restrict__ out)
{
    int idx = blockIdx.x * 256 + threadIdx.x;      // token (b,h2,w2)
    int w2 = idx & 127, h2 = (idx >> 7) & 127, b = idx >> 14;
    const float* ib = in + (size_t)b * CI * 65536;
    float acc[CO];
#pragma unroll
    for (int co = 0; co < CO; co++) acc[co] = bias[co];
    int h0 = 2 * h2 - 1, w0 = 2 * w2 - 1;
    for (int ci = 0; ci < CI; ci++) {
        float t[9];
#pragma unroll
        for (int ky = 0; ky < 3; ky++)
#pragma unroll
            for (int kx = 0; kx < 3; kx++) {
                int hh = h0 + ky, ww = w0 + kx;
                bool ok = ((unsigned)hh < 256u) && ((unsigned)ww < 256u);
                t[ky * 3 + kx] = ok ? ib[((size_t)ci << 16) + (hh << 8) + ww] : 0.f;
            }
#pragma unroll
        for (int co = 0; co < CO; co++)
#pragma unroll
            for (int k = 0; k < 9; k++)
                acc[co] += t[k] * wgt[(co * CI + ci) * 9 + k];   // uniform -> s_load
    }
    float* ob = out + (size_t)idx * CO;
#pragma unroll
    for (int co = 0; co < CO; co++) ob[co] = silu_f(acc[co]);
}

// ---------------- softmax(z @ cell_k^T / 4) -> w [T,32] ----------------
__global__ __launch_bounds__(256) void memcell_w_kern(
    const float* __restrict__ z, const float* __restrict__ ck, float* __restrict__ wout)
{
    int t = blockIdx.x * 256 + threadIdx.x;
    float zv[16];
    const float4* zp = (const float4*)(z + (size_t)t * 16);
#pragma unroll
    for (int i = 0; i < 4; i++) {
        float4 v = zp[i];
        zv[4 * i] = v.x; zv[4 * i + 1] = v.y; zv[4 * i + 2] = v.z; zv[4 * i + 3] = v.w;
    }
    float lg[32]; float mx = -1e30f;
#pragma unroll
    for (int m = 0; m < 32; m++) {
        float a = 0.f;
#pragma unroll
        for (int n = 0; n < 16; n++) a += zv[n] * ck[m * 16 + n];
        a *= 0.25f;
        lg[m] = a; mx = fmaxf(mx, a);
    }
    float s = 0.f;
#pragma unroll
    for (int m = 0; m < 32; m++) { lg[m] = __expf(lg[m] - mx); s += lg[m]; }
    float inv = 1.f / s;
    float4* wp = (float4*)(wout + (size_t)t * 32);
#pragma unroll
    for (int m = 0; m < 8; m++)
        wp[m] = make_float4(lg[4 * m] * inv, lg[4 * m + 1] * inv,
                            lg[4 * m + 2] * inv, lg[4 * m + 3] * inv);
}

// ---------------- WtW = w^T w [32,32], WtT = w^T t_star [32,128] ----------------
__global__ __launch_bounds__(256) void memcell_acc_kern(
    const float* __restrict__ wmat, const float* __restrict__ tstar,
    float* __restrict__ WtW, float* __restrict__ WtT)
{
    __shared__ float ws[64][32];
    __shared__ float ts[64][128];
    int tid = threadIdx.x;
    int sg = tid & 31, mg = tid >> 5;        // WtT tile
    int mW = tid & 31, m2 = (tid >> 5) * 4;  // WtW tile
    float accT[16], accW[4];
#pragma unroll
    for (int i = 0; i < 16; i++) accT[i] = 0.f;
#pragma unroll
    for (int i = 0; i < 4; i++) accW[i] = 0.f;

    for (int c = blockIdx.x; c < 2048; c += 256) {
        size_t base = (size_t)c * 64;
        __syncthreads();
        {
            const float4* src = (const float4*)(wmat + base * 32);
            float4* dst = (float4*)&ws[0][0];
#pragma unroll
            for (int i = 0; i < 2; i++) dst[tid + 256 * i] = src[tid + 256 * i];
            const float4* src2 = (const float4*)(tstar + base * 128);
            float4* dst2 = (float4*)&ts[0][0];
#pragma unroll
            for (int i = 0; i < 8; i++) dst2[tid + 256 * i] = src2[tid + 256 * i];
        }
        __syncthreads();
        for (int t = 0; t < 64; t++) {
            float wv[4];
#pragma unroll
            for (int i = 0; i < 4; i++) wv[i] = ws[t][mg * 4 + i];
            float4 sv = *(const float4*)&ts[t][sg * 4];
#pragma unroll
            for (int i = 0; i < 4; i++) {
                accT[i * 4 + 0] += wv[i] * sv.x; accT[i * 4 + 1] += wv[i] * sv.y;
                accT[i * 4 + 2] += wv[i] * sv.z; accT[i * 4 + 3] += wv[i] * sv.w;
            }
            float wa = ws[t][mW];
            float4 wb = *(const float4*)&ws[t][m2];
            accW[0] += wa * wb.x; accW[1] += wa * wb.y;
            accW[2] += wa * wb.z; accW[3] += wa * wb.w;
        }
    }
#pragma unroll
    for (int i = 0; i < 4; i++)
#pragma unroll
        for (int j = 0; j < 4; j++)
            atomicAdd(&WtT[(mg * 4 + i) * 128 + sg * 4 + j], accT[i * 4 + j]);
#pragma unroll
    for (int j = 0; j < 4; j++)
        atomicAdd(&WtW[mW * 32 + m2 + j], accW[j]);
}

// ------- cell_v_new = cell_v + ALPHA*(WtT - WtW @ cell_v)  [32,128] -------
__global__ __launch_bounds__(256) void cvnew_kern(
    const float* __restrict__ cv, const float* __restrict__ WtW,
    const float* __restrict__ WtT, float* __restrict__ cvn)
{
    int idx = blockIdx.x * 256 + threadIdx.x;   // 4096
    int s = idx & 127, m = idx >> 7;
    float g = WtT[idx];
#pragma unroll
    for (int j = 0; j < 32; j++) g -= WtW[m * 32 + j] * cv[j * 128 + s];
    cvn[idx] = cv[idx] + ALPHA_F * g;
}

// ------- t_read = w @ cell_v_new, scattered to NCHW d0m [8,128,128,128] -------
__global__ __launch_bounds__(256) void memcell_read_kern(
    const float* __restrict__ wmat, const float* __restrict__ cvn, float* __restrict__ d0m)
{
    int t = blockIdx.x * 256 + threadIdx.x;
    int w2 = t & 127, h2 = (t >> 7) & 127, b = t >> 14;
    float wv[32];
    const float4* wp = (const float4*)(wmat + (size_t)t * 32);
#pragma unroll
    for (int i = 0; i < 8; i++) {
        float4 v = wp[i];
        wv[4 * i] = v.x; wv[4 * i + 1] = v.y; wv[4 * i + 2] = v.z; wv[4 * i + 3] = v.w;
    }
    float* ob = d0m + (size_t)b * 128 * 16384 + (h2 << 7) + w2;
    for (int s = 0; s < 128; s++) {
        float a = 0.f;
#pragma unroll
        for (int m = 0; m < 32; m++) a += wv[m] * cvn[m * 128 + s];  // uniform -> s_load
        ob[(size_t)s * 16384] = a;
    }
}

// ------- ConvTranspose2d(128->3, k4, s2, p1) + bias + silu, all 4 parities/thread -------
__global__ __launch_bounds__(256) void deconv_silu_kern(
    const float* __restrict__ in, const float* __restrict__ dw,
    const float* __restrict__ db, float* __restrict__ out)
{
    int g = blockIdx.x;                   // 512: b*64 + hb*8 + wb
    int wb = g & 7, hb = (g >> 3) & 7, b = g >> 6;
    int tx = threadIdx.x & 15, ty = threadIdx.x >> 4;
    int h2 = hb * 16 + ty, w2 = wb * 16 + tx;

    float mh[3], mw[3];
    int ihc[3], iwc[3];
#pragma unroll
    for (int a = 0; a < 3; a++) {
        int v = h2 - 1 + a;
        mh[a] = ((unsigned)v < 128u) ? 1.f : 0.f;
        ihc[a] = v < 0 ? 0 : (v > 127 ? 127 : v);
        v = w2 - 1 + a;
        mw[a] = ((unsigned)v < 128u) ? 1.f : 0.f;
        iwc[a] = v < 0 ? 0 : (v > 127 ? 127 : v);
    }
    const float* base = in + (size_t)b * 128 * 16384;
    const float* p[3][3];
    float msk[3][3];
#pragma unroll
    for (int a = 0; a < 3; a++)
#pragma unroll
        for (int c = 0; c < 3; c++) {
            p[a][c] = base + (ihc[a] << 7) + iwc[c];
            msk[a][c] = mh[a] * mw[c];
        }

    float acc[2][2][3];
#pragma unroll
    for (int ph = 0; ph < 2; ph++)
#pragma unroll
        for (int pw = 0; pw < 2; pw++)
#pragma unroll
            for (int co = 0; co < 3; co++) acc[ph][pw][co] = db[co];

    const int RA[4] = {0, 1, 1, 2}, RP[4] = {0, 0, 1, 1}, RK[4] = {3, 1, 2, 0};

    for (int ci = 0; ci < 128; ci++) {
        float t[3][3];
#pragma unroll
        for (int a = 0; a < 3; a++)
#pragma unroll
            for (int c = 0; c < 3; c++)
                t[a][c] = msk[a][c] * p[a][c][(size_t)ci << 14];
        const float* wc = dw + ci * 48;     // [co][kh][kw], uniform -> s_load
#pragma unroll
        for (int ri = 0; ri < 4; ri++)
#pragma unroll
            for (int cj = 0; cj < 4; cj++) {
                float tv = t[RA[ri]][RA[cj]];
                int ph = RP[ri], pw = RP[cj];
                int widx = RK[ri] * 4 + RK[cj];
#pragma unroll
                for (int co = 0; co < 3; co++)
                    acc[ph][pw][co] += tv * wc[co * 16 + widx];
            }
    }
    int h = 2 * h2, w = 2 * w2;
#pragma unroll
    for (int ph = 0; ph < 2; ph++)
#pragma unroll
        for (int co = 0; co < 3; co++) {
            float2 v = make_float2(silu_f(acc[ph][0][co]), silu_f(acc[ph][1][co]));
            *(float2*)&out[(size_t)b * 3 * 65536 + (size_t)co * 65536 + ((size_t)(h + ph) << 8) + w] = v;
        }
}

extern "C" void kernel_launch(void* const* d_in, const int* in_sizes, int n_in,
                              void* d_out, int out_size, void* d_ws, size_t ws_size,
                              hipStream_t stream)
{
    const float* x      = (const float*)d_in[0];
    const float* e0n_w1 = (const float*)d_in[1];
    const float* e0n_b1 = (const float*)d_in[2];
    const float* e0n_w2 = (const float*)d_in[3];
    const float* e0n_b2 = (const float*)d_in[4];
    const float* e0s_w1 = (const float*)d_in[5];
    const float* e0s_b1 = (const float*)d_in[6];
    const float* e0s_w2 = (const float*)d_in[7];
    const float* e0s_b2 = (const float*)d_in[8];
    const float* d0_dw  = (const float*)d_in[9];
    const float* d0_db  = (const float*)d_in[10];
    const float* d0_cw  = (const float*)d_in[11];
    const float* d0_cb  = (const float*)d_in[12];
    const float* cell_k = (const float*)d_in[13];
    const float* cell_v = (const float*)d_in[14];
    float* outp = (float*)d_out;

    char* ws = (char*)d_ws;
    __hip_bfloat16* a_s = (__hip_bfloat16*)(ws);
    float* t_star = (float*)(ws + 134217728);
    float* a_n    = (float*)(ws + 201326592);
    __hip_bfloat16* wt2 = (__hip_bfloat16*)(ws + 201326592);  // reuses a_n after conv2_n
    float* z      = (float*)(ws + 234881024);
    float* wmat   = (float*)(ws + 243269632);
    float* WtW    = (float*)(ws + 260046848);
    float* WtT    = (float*)(ws + 260050944);
    float* cvn    = (float*)(ws + 260067328);
    float* d0m    = (float*)(ws);               // reuse a_s region
    float* dec1   = (float*)(ws + 67108864);    // reuse a_s region (tail)

    // n-branch encoder (a_n dead after conv2s2_silu)
    conv1_silu<16><<<2048, 256, 0, stream>>>(x, e0n_w1, e0n_b1, a_n);
    conv2s2_silu<16, 16><<<512, 256, 0, stream>>>(a_n, e0n_w2, e0n_b2, z);
    // s-branch encoder: NC8HW8 MFMA conv1 -> MFMA implicit-GEMM conv2
    wprep_kern<<<576, 256, 0, stream>>>(e0s_w2, wt2);
    conv1s_mfma<<<4096, 256, 0, stream>>>(x, e0s_w1, e0s_b1, a_s);
    conv2s_mfma<<<2048, 256, 0, stream>>>(a_s, wt2, e0s_b2, t_star);
    // memcell
    memcell_w_kern<<<512, 256, 0, stream>>>(z, cell_k, wmat);
    hipMemsetAsync(WtW, 0, (1024 + 4096) * sizeof(float), stream);
    memcell_acc_kern<<<256, 256, 0, stream>>>(wmat, t_star, WtW, WtT);
    cvnew_kern<<<16, 256, 0, stream>>>(cell_v, WtW, WtT, cvn);
    memcell_read_kern<<<512, 256, 0, stream>>>(wmat, cvn, d0m);
    // decoder
    deconv_silu_kern<<<512, 256, 0, stream>>>(d0m, d0_dw, d0_db, dec1);
    conv1_silu<3><<<2048, 256, 0, stream>>>(dec1, d0_cw, d0_cb, outp);
}

// Round 6
// 412.139 us; speedup vs baseline: 5.6390x; 1.1492x over previous
//
#include <hip/hip_runtime.h>
#include <hip/hip_bf16.h>

// CPSFMemcellAutoencoder: B=8, 256x256 input, N=16, S=128, M=32, T=131072.
// Workspace layout (~260 MB):
//   [0, 134217728)            a_s   : NC8HW8 [8][16 cig][65536 hw][8 ci] bf16
//   [134217728, 167772160)    t_star: [T,128] bf16 token-major (only memcell_acc reads it)
//   [201326592, 234881024)    a_n   : [8,16,256,256] f32 (n-branch)
//     REUSED: wt2  at +201326592 (294912 B, conv2_s weights bf16)
//     REUSED: part at +201850880 (1024 x 5120 f32 = 20.97 MB partials; a_n dead by then)
//   [234881024, 243269632)    z     : [T,16] f32
//   [243269632, 260046848)    wmat  : [T,32] f32
//   [260046848, 260050944)    WtW   : [32,32] f32 (zeroed, reduce-atomics)
//   [260050944, 260067328)    WtT   : [32,128] f32
//   [260067328, 260083712)    cvn   : [32,128] f32
//   d0m  reuses [0, 67108864)        : [8,128,128,128] f32
//   dec1 reuses [67108864, 73400320) : [8,3,256,256] f32

#define ALPHA_F 1e-6f

typedef __attribute__((ext_vector_type(8))) short bf16x8;
typedef __attribute__((ext_vector_type(4))) float f32x4;

__device__ __forceinline__ float silu_f(float x) {
    return x / (1.f + __expf(-x));
}

__device__ __forceinline__ short f2bf(float f) {
    __hip_bfloat16 h = __float2bfloat16(f);
    union { __hip_bfloat16 b; short s; } u; u.b = h; return u.s;
}

__device__ __forceinline__ float bf2f(unsigned short s) {
    union { unsigned u; float f; } c; c.u = (unsigned)s << 16; return c.f;
}

// ---------------- conv 3x3, Cin=3, stride 1, pad 1, + bias + silu (NCHW f32 out) ----------------
template<int CO>
__global__ __launch_bounds__(256) void conv1_silu(
    const float* __restrict__ x, const float* __restrict__ wgt,
    const float* __restrict__ bias, float* __restrict__ out)
{
    int idx = blockIdx.x * 256 + threadIdx.x;      // (b,h,w)
    int w = idx & 255, h = (idx >> 8) & 255, b = idx >> 16;
    const float* xb = x + (size_t)b * 3 * 65536;
    float in[27];
#pragma unroll
    for (int ci = 0; ci < 3; ci++)
#pragma unroll
        for (int ky = 0; ky < 3; ky++)
#pragma unroll
            for (int kx = 0; kx < 3; kx++) {
                int hh = h + ky - 1, ww = w + kx - 1;
                bool ok = ((unsigned)hh < 256u) && ((unsigned)ww < 256u);
                in[(ci * 3 + ky) * 3 + kx] = ok ? xb[(ci << 16) + (hh << 8) + ww] : 0.f;
            }
    float* ob = out + (size_t)b * CO * 65536 + (h << 8) + w;
#pragma unroll 4
    for (int co = 0; co < CO; co++) {
        float acc = bias[co];          // uniform index -> s_load
#pragma unroll
        for (int k = 0; k < 27; k++) acc += in[k] * wgt[co * 27 + k];
        ob[(size_t)co << 16] = silu_f(acc);
    }
}

// ---------------- s-branch conv1 as single-K-step MFMA GEMM ----------------
#define C1K 40   // padded k-stride (shorts)
__global__ __launch_bounds__(256) void conv1s_mfma(
    const float* __restrict__ x, const float* __restrict__ wgt,
    const float* __restrict__ bias, __hip_bfloat16* __restrict__ out)
{
    __shared__ __align__(16) short Ps[128 * C1K];  // [pixel][k]
    __shared__ __align__(16) short Ws[128 * C1K];  // [co][k]
    int tid = threadIdx.x;
    int g = blockIdx.x;                 // 4096: b*512 + rem
    int b = g >> 9, rem = g & 511;
    int h = rem >> 1, w0 = (rem & 1) * 128;

    union { short s[32]; float4 v4[4]; } row;
#pragma unroll
    for (int k = 0; k < 32; k++) row.s[k] = 0;
    if (tid < 128) {
        int wpix = w0 + tid;
        const float* xb = x + (size_t)b * 3 * 65536;
#pragma unroll
        for (int ci = 0; ci < 3; ci++)
#pragma unroll
            for (int ky = 0; ky < 3; ky++)
#pragma unroll
                for (int kx = 0; kx < 3; kx++) {
                    int hh = h + ky - 1, ww = wpix + kx - 1;
                    float v = 0.f;
                    if (((unsigned)hh < 256u) && ((unsigned)ww < 256u))
                        v = xb[(ci << 16) + (hh << 8) + ww];
                    row.s[ci * 9 + ky * 3 + kx] = f2bf(v);
                }
#pragma unroll
        for (int j = 0; j < 4; j++) *(float4*)&Ps[tid * C1K + j * 8] = row.v4[j];
    } else {
        int co = tid - 128;
#pragma unroll
        for (int k = 0; k < 27; k++) row.s[k] = f2bf(wgt[co * 27 + k]);
#pragma unroll
        for (int j = 0; j < 4; j++) *(float4*)&Ws[co * C1K + j * 8] = row.v4[j];
    }
    __syncthreads();

    int lane = tid & 63, wave = tid >> 6;
    int coH = (wave & 1) * 64, pxH = (wave >> 1) * 64;
    int r16 = lane & 15, koff = (lane >> 4) * 8;
    bf16x8 af[4], bfr[4];
#pragma unroll
    for (int mt = 0; mt < 4; mt++)
        af[mt] = *(bf16x8*)&Ws[(coH + mt * 16 + r16) * C1K + koff];
#pragma unroll
    for (int nt = 0; nt < 4; nt++)
        bfr[nt] = *(bf16x8*)&Ps[(pxH + nt * 16 + r16) * C1K + koff];
    f32x4 acc[4][4];
#pragma unroll
    for (int mt = 0; mt < 4; mt++)
#pragma unroll
        for (int nt = 0; nt < 4; nt++) {
#pragma unroll
            for (int r = 0; r < 4; r++) acc[mt][nt][r] = 0.f;
            acc[mt][nt] = __builtin_amdgcn_mfma_f32_16x16x32_bf16(
                af[mt], bfr[nt], acc[mt][nt], 0, 0, 0);
        }

    __hip_bfloat16* ob = out + (size_t)b * 16 * 65536 * 8;
#pragma unroll
    for (int mt = 0; mt < 4; mt++) {
        int cb = coH + mt * 16 + (lane >> 4) * 4;
        float4 bv = *(const float4*)&bias[cb];
        float bvals[4] = {bv.x, bv.y, bv.z, bv.w};
        int cig = cb >> 3, cof = cb & 7;
#pragma unroll
        for (int nt = 0; nt < 4; nt++) {
            int p = pxH + nt * 16 + r16;
            int hw = (h << 8) + w0 + p;
            union { short s[4]; float2 v; } u;
#pragma unroll
            for (int r = 0; r < 4; r++)
                u.s[r] = f2bf(silu_f(acc[mt][nt][r] + bvals[r]));
            *(float2*)&ob[((size_t)cig * 65536 + hw) * 8 + cof] = u.v;
        }
    }
}

// ---------------- weight prep: Wt[pos][co][ci] bf16 from W[co][ci][ky][kx] f32 ----------------
__global__ __launch_bounds__(256) void wprep_kern(
    const float* __restrict__ w, __hip_bfloat16* __restrict__ wt)
{
    int i = blockIdx.x * 256 + threadIdx.x;        // 147456
    int pos = i >> 14, rem = i & 16383;
    int co = rem >> 7, ci = rem & 127;
    wt[i] = __float2bfloat16(w[co * 1152 + ci * 9 + pos]);
}

// ------------- conv2_s as implicit GEMM: M=T x N=128co x K=1152, bf16 MFMA -------------
#define LDSK 40
__global__ __launch_bounds__(256) void conv2s_mfma(
    const __hip_bfloat16* __restrict__ a_s,   // NC8HW8 [8][16][65536][8]
    const __hip_bfloat16* __restrict__ wt,    // [9][128co][128ci]
    const float* __restrict__ bias, __hip_bfloat16* __restrict__ out)  // [T][128] bf16
{
    __shared__ __align__(16) short As[64 * LDSK];
    __shared__ __align__(16) short Bs[128 * LDSK];
    int tid = threadIdx.x;
    int g = blockIdx.x;                 // 2048 tiles
    int b = g >> 8, h2 = (g >> 1) & 127, w2base = (g & 1) * 64;
    int lane = tid & 63, wave = tid >> 6;

    int tokA = tid >> 2, cqA = tid & 3;
    int w2A = w2base + tokA;
    int mrow = lane & 15, koff8 = (lane >> 4) * 8;

    f32x4 acc[2][4];
#pragma unroll
    for (int i = 0; i < 2; i++)
#pragma unroll
        for (int j = 0; j < 4; j++)
#pragma unroll
            for (int r = 0; r < 4; r++) acc[i][j][r] = 0.f;

    const float4* ab8 = (const float4*)a_s + (size_t)b * 16 * 65536;

    for (int pos = 0; pos < 9; pos++) {
        int ky = pos / 3, kx = pos - 3 * ky;
        int y = 2 * h2 - 1 + ky;
        int x = 2 * w2A - 1 + kx;
        bool okA = ((unsigned)y < 256u) && ((unsigned)x < 256u);
        int pix = (y << 8) + x;
        const __hip_bfloat16* wp = wt + (size_t)pos * 16384;
#pragma unroll 1
        for (int cc = 0; cc < 4; cc++) {
            float4 av = make_float4(0.f, 0.f, 0.f, 0.f);
            if (okA) av = ab8[(size_t)(cc * 4 + cqA) * 65536 + pix];
            int c1 = tid + 256;
            float4 b0 = *(const float4*)(wp + (size_t)(tid >> 2) * 128 + cc * 32 + (tid & 3) * 8);
            float4 b1 = *(const float4*)(wp + (size_t)(c1 >> 2) * 128 + cc * 32 + (c1 & 3) * 8);
            __syncthreads();
            *(float4*)&As[tokA * LDSK + cqA * 8] = av;
            *(float4*)&Bs[(tid >> 2) * LDSK + (tid & 3) * 8] = b0;
            *(float4*)&Bs[(c1 >> 2) * LDSK + (c1 & 3) * 8] = b1;
            __syncthreads();
            bf16x8 bfr[2], afr[4];
#pragma unroll
            for (int nt = 0; nt < 2; nt++)
                bfr[nt] = *(bf16x8*)&Bs[(wave * 32 + nt * 16 + mrow) * LDSK + koff8];
#pragma unroll
            for (int mt = 0; mt < 4; mt++)
                afr[mt] = *(bf16x8*)&As[(mt * 16 + mrow) * LDSK + koff8];
#pragma unroll
            for (int nt = 0; nt < 2; nt++)
#pragma unroll
                for (int mt = 0; mt < 4; mt++)
                    acc[nt][mt] = __builtin_amdgcn_mfma_f32_16x16x32_bf16(
                        afr[mt], bfr[nt], acc[nt][mt], 0, 0, 0);
        }
    }
    int rowg = (lane >> 4) * 4;
    size_t tbase = (size_t)g * 64;
#pragma unroll
    for (int nt = 0; nt < 2; nt++) {
        int co = wave * 32 + nt * 16 + (lane & 15);
        float bv = bias[co];
#pragma unroll
        for (int mt = 0; mt < 4; mt++)
#pragma unroll
            for (int r = 0; r < 4; r++) {
                int m = mt * 16 + rowg + r;
                out[(tbase + m) * 128 + co] = __float2bfloat16(silu_f(acc[nt][mt][r] + bv));
            }
    }
}

// ------------- conv 3x3, stride 2, pad 1, + bias + silu, token-major out (n-branch) -------------
template<int CI, int CO>
__global__ __launch_bounds__(256) void conv2s2_silu(
    const float* __restrict__ in, const float* __restrict__ wgt,
    const float* __restrict__ bias, float* __restrict__ out)
{
    int idx = blockIdx.x * 256 + threadIdx.x;      // token (b,h2,w2)
    int w2 = idx & 127, h2 = (idx >> 7) & 127, b = idx >> 14;
    const float* ib = in + (size_t)b * CI * 65536;
    float acc[CO];
#pragma unroll
    for (int co = 0; co < CO; co++) acc[co] = bias[co];
    int h0 = 2 * h2 - 1, w0 = 2 * w2 - 1;
    for (int ci = 0; ci < CI; ci++) {
        float t[9];
#pragma unroll
        for (int ky = 0; ky < 3; ky++)
#pragma unroll
            for (int kx = 0; kx < 3; kx++) {
                int hh = h0 + ky, ww = w0 + kx;
                bool ok = ((unsigned)hh < 256u) && ((unsigned)ww < 256u);
                t[ky * 3 + kx] = ok ? ib[((size_t)ci << 16) + (hh << 8) + ww] : 0.f;
            }
#pragma unroll
        for (int co = 0; co < CO; co++)
#pragma unroll
            for (int k = 0; k < 9; k++)
                acc[co] += t[k] * wgt[(co * CI + ci) * 9 + k];
    }
    float* ob = out + (size_t)idx * CO;
#pragma unroll
    for (int co = 0; co < CO; co++) ob[co] = silu_f(acc[co]);
}

// ---------------- softmax(z @ cell_k^T / 4) -> w [T,32] ----------------
__global__ __launch_bounds__(256) void memcell_w_kern(
    const float* __restrict__ z, const float* __restrict__ ck, float* __restrict__ wout)
{
    int t = blockIdx.x * 256 + threadIdx.x;
    float zv[16];
    const float4* zp = (const float4*)(z + (size_t)t * 16);
#pragma unroll
    for (int i = 0; i < 4; i++) {
        float4 v = zp[i];
        zv[4 * i] = v.x; zv[4 * i + 1] = v.y; zv[4 * i + 2] = v.z; zv[4 * i + 3] = v.w;
    }
    float lg[32]; float mx = -1e30f;
#pragma unroll
    for (int m = 0; m < 32; m++) {
        float a = 0.f;
#pragma unroll
        for (int n = 0; n < 16; n++) a += zv[n] * ck[m * 16 + n];
        a *= 0.25f;
        lg[m] = a; mx = fmaxf(mx, a);
    }
    float s = 0.f;
#pragma unroll
    for (int m = 0; m < 32; m++) { lg[m] = __expf(lg[m] - mx); s += lg[m]; }
    float inv = 1.f / s;
    float4* wp = (float4*)(wout + (size_t)t * 32);
#pragma unroll
    for (int m = 0; m < 8; m++)
        wp[m] = make_float4(lg[4 * m] * inv, lg[4 * m + 1] * inv,
                            lg[4 * m + 2] * inv, lg[4 * m + 3] * inv);
}

// ---------------- WtW/WtT partials: 1024 blocks x 128 tokens, no atomics ----------------
// part[block][5120]: [0,4096) = accT (i*256+tid), [4096,5120) = accW
__global__ __launch_bounds__(256) void memcell_acc_kern(
    const float* __restrict__ wmat, const __hip_bfloat16* __restrict__ tstar,
    float* __restrict__ part)
{
    __shared__ float ws[64][32];     // 8 KB
    __shared__ float ts[64 * 128];   // 32 KB
    int tid = threadIdx.x;
    int sg = tid & 31, mg = tid >> 5;        // WtT tile: rows mg*4.., cols sg*4..
    int mW = tid & 31, m2 = (tid >> 5) * 4;  // WtW tile
    float accT[16], accW[4];
#pragma unroll
    for (int i = 0; i < 16; i++) accT[i] = 0.f;
#pragma unroll
    for (int i = 0; i < 4; i++) accW[i] = 0.f;

#pragma unroll 1
    for (int cc = 0; cc < 2; cc++) {
        int c = blockIdx.x * 2 + cc;
        size_t base = (size_t)c * 64;
        __syncthreads();
        {
            const float4* src = (const float4*)(wmat + base * 32);
            float4* dst = (float4*)&ws[0][0];
#pragma unroll
            for (int i = 0; i < 2; i++) dst[tid + 256 * i] = src[tid + 256 * i];
            const float4* src2 = (const float4*)(tstar + base * 128);  // 8 bf16 each
#pragma unroll
            for (int i = 0; i < 4; i++) {
                union { float4 v; unsigned short us[8]; } u;
                u.v = src2[tid + 256 * i];
                float* d = &ts[(tid + 256 * i) * 8];
                float4 lo = make_float4(bf2f(u.us[0]), bf2f(u.us[1]), bf2f(u.us[2]), bf2f(u.us[3]));
                float4 hi = make_float4(bf2f(u.us[4]), bf2f(u.us[5]), bf2f(u.us[6]), bf2f(u.us[7]));
                *(float4*)d = lo; *(float4*)(d + 4) = hi;
            }
        }
        __syncthreads();
        for (int t = 0; t < 64; t++) {
            float4 wv = *(const float4*)&ws[t][mg * 4];
            float4 sv = *(const float4*)&ts[t * 128 + sg * 4];
            accT[0]  += wv.x * sv.x; accT[1]  += wv.x * sv.y; accT[2]  += wv.x * sv.z; accT[3]  += wv.x * sv.w;
            accT[4]  += wv.y * sv.x; accT[5]  += wv.y * sv.y; accT[6]  += wv.y * sv.z; accT[7]  += wv.y * sv.w;
            accT[8]  += wv.z * sv.x; accT[9]  += wv.z * sv.y; accT[10] += wv.z * sv.z; accT[11] += wv.z * sv.w;
            accT[12] += wv.w * sv.x; accT[13] += wv.w * sv.y; accT[14] += wv.w * sv.z; accT[15] += wv.w * sv.w;
            float wa = ws[t][mW];
            float4 wb = *(const float4*)&ws[t][m2];
            accW[0] += wa * wb.x; accW[1] += wa * wb.y;
            accW[2] += wa * wb.z; accW[3] += wa * wb.w;
        }
    }
    float* pb = part + (size_t)blockIdx.x * 5120;
#pragma unroll
    for (int i = 0; i < 16; i++) pb[i * 256 + tid] = accT[i];
#pragma unroll
    for (int i = 0; i < 4; i++) pb[4096 + i * 256 + tid] = accW[i];
}

// ---------------- reduce 1024 partials -> WtT [32,128], WtW [32,32] ----------------
// grid 320x256: 16 segments of 64 partial-blocks per output slot; atomics (16/slot).
__global__ __launch_bounds__(256) void memcell_reduce_kern(
    const float* __restrict__ part, float* __restrict__ WtT, float* __restrict__ WtW)
{
    int gid = blockIdx.x * 256 + threadIdx.x;   // 81920
    int j = gid % 5120, seg = gid / 5120;
    const float* p = part + (size_t)seg * 64 * 5120 + j;
    float s = 0.f;
#pragma unroll 8
    for (int k = 0; k < 64; k++) s += p[(size_t)k * 5120];
    int i = j >> 8, t = j & 255;
    if (j < 4096) {
        int sg = t & 31, mg = t >> 5;
        atomicAdd(&WtT[(mg * 4 + (i >> 2)) * 128 + sg * 4 + (i & 3)], s);
    } else {
        int i2 = i - 16;
        int mW = t & 31, m2 = (t >> 5) * 4;
        atomicAdd(&WtW[mW * 32 + m2 + i2], s);
    }
}

// ------- cell_v_new = cell_v + ALPHA*(WtT - WtW @ cell_v)  [32,128] -------
__global__ __launch_bounds__(256) void cvnew_kern(
    const float* __restrict__ cv, const float* __restrict__ WtW,
    const float* __restrict__ WtT, float* __restrict__ cvn)
{
    int idx = blockIdx.x * 256 + threadIdx.x;   // 4096
    int s = idx & 127, m = idx >> 7;
    float g = WtT[idx];
#pragma unroll
    for (int j = 0; j < 32; j++) g -= WtW[m * 32 + j] * cv[j * 128 + s];
    cvn[idx] = cv[idx] + ALPHA_F * g;
}

// ------- t_read = w @ cell_v_new, scattered to NCHW d0m [8,128,128,128] -------
__global__ __launch_bounds__(256) void memcell_read_kern(
    const float* __restrict__ wmat, const float* __restrict__ cvn, float* __restrict__ d0m)
{
    int t = blockIdx.x * 256 + threadIdx.x;
    int w2 = t & 127, h2 = (t >> 7) & 127, b = t >> 14;
    float wv[32];
    const float4* wp = (const float4*)(wmat + (size_t)t * 32);
#pragma unroll
    for (int i = 0; i < 8; i++) {
        float4 v = wp[i];
        wv[4 * i] = v.x; wv[4 * i + 1] = v.y; wv[4 * i + 2] = v.z; wv[4 * i + 3] = v.w;
    }
    float* ob = d0m + (size_t)b * 128 * 16384 + (h2 << 7) + w2;
    for (int s = 0; s < 128; s++) {
        float a = 0.f;
#pragma unroll
        for (int m = 0; m < 32; m++) a += wv[m] * cvn[m * 128 + s];
        ob[(size_t)s * 16384] = a;
    }
}

// ------- ConvTranspose2d(128->3, k4, s2, p1) + bias + silu, all 4 parities/thread -------
__global__ __launch_bounds__(256) void deconv_silu_kern(
    const float* __restrict__ in, const float* __restrict__ dw,
    const float* __restrict__ db, float* __restrict__ out)
{
    int g = blockIdx.x;                   // 512: b*64 + hb*8 + wb
    int wb = g & 7, hb = (g >> 3) & 7, b = g >> 6;
    int tx = threadIdx.x & 15, ty = threadIdx.x >> 4;
    int h2 = hb * 16 + ty, w2 = wb * 16 + tx;

    float mh[3], mw[3];
    int ihc[3], iwc[3];
#pragma unroll
    for (int a = 0; a < 3; a++) {
        int v = h2 - 1 + a;
        mh[a] = ((unsigned)v < 128u) ? 1.f : 0.f;
        ihc[a] = v < 0 ? 0 : (v > 127 ? 127 : v);
        v = w2 - 1 + a;
        mw[a] = ((unsigned)v < 128u) ? 1.f : 0.f;
        iwc[a] = v < 0 ? 0 : (v > 127 ? 127 : v);
    }
    const float* base = in + (size_t)b * 128 * 16384;
    const float* p[3][3];
    float msk[3][3];
#pragma unroll
    for (int a = 0; a < 3; a++)
#pragma unroll
        for (int c = 0; c < 3; c++) {
            p[a][c] = base + (ihc[a] << 7) + iwc[c];
            msk[a][c] = mh[a] * mw[c];
        }

    float acc[2][2][3];
#pragma unroll
    for (int ph = 0; ph < 2; ph++)
#pragma unroll
        for (int pw = 0; pw < 2; pw++)
#pragma unroll
            for (int co = 0; co < 3; co++) acc[ph][pw][co] = db[co];

    const int RA[4] = {0, 1, 1, 2}, RP[4] = {0, 0, 1, 1}, RK[4] = {3, 1, 2, 0};

    for (int ci = 0; ci < 128; ci++) {
        float t[3][3];
#pragma unroll
        for (int a = 0; a < 3; a++)
#pragma unroll
            for (int c = 0; c < 3; c++)
                t[a][c] = msk[a][c] * p[a][c][(size_t)ci << 14];
        const float* wc = dw + ci * 48;
#pragma unroll
        for (int ri = 0; ri < 4; ri++)
#pragma unroll
            for (int cj = 0; cj < 4; cj++) {
                float tv = t[RA[ri]][RA[cj]];
                int ph = RP[ri], pw = RP[cj];
                int widx = RK[ri] * 4 + RK[cj];
#pragma unroll
                for (int co = 0; co < 3; co++)
                    acc[ph][pw][co] += tv * wc[co * 16 + widx];
            }
    }
    int h = 2 * h2, w = 2 * w2;
#pragma unroll
    for (int ph = 0; ph < 2; ph++)
#pragma unroll
        for (int co = 0; co < 3; co++) {
            float2 v = make_float2(silu_f(acc[ph][0][co]), silu_f(acc[ph][1][co]));
            *(float2*)&out[(size_t)b * 3 * 65536 + (size_t)co * 65536 + ((size_t)(h + ph) << 8) + w] = v;
        }
}

extern "C" void kernel_launch(void* const* d_in, const int* in_sizes, int n_in,
                              void* d_out, int out_size, void* d_ws, size_t ws_size,
                              hipStream_t stream)
{
    const float* x      = (const float*)d_in[0];
    const float* e0n_w1 = (const float*)d_in[1];
    const float* e0n_b1 = (const float*)d_in[2];
    const float* e0n_w2 = (const float*)d_in[3];
    const float* e0n_b2 = (const float*)d_in[4];
    const float* e0s_w1 = (const float*)d_in[5];
    const float* e0s_b1 = (const float*)d_in[6];
    const float* e0s_w2 = (const float*)d_in[7];
    const float* e0s_b2 = (const float*)d_in[8];
    const float* d0_dw  = (const float*)d_in[9];
    const float* d0_db  = (const float*)d_in[10];
    const float* d0_cw  = (const float*)d_in[11];
    const float* d0_cb  = (const float*)d_in[12];
    const float* cell_k = (const float*)d_in[13];
    const float* cell_v = (const float*)d_in[14];
    float* outp = (float*)d_out;

    char* ws = (char*)d_ws;
    __hip_bfloat16* a_s    = (__hip_bfloat16*)(ws);
    __hip_bfloat16* t_star = (__hip_bfloat16*)(ws + 134217728);
    float* a_n    = (float*)(ws + 201326592);
    __hip_bfloat16* wt2 = (__hip_bfloat16*)(ws + 201326592);  // reuses a_n after conv2_n
    float* part   = (float*)(ws + 201850880);                 // 21 MB partials (a_n dead)
    float* z      = (float*)(ws + 234881024);
    float* wmat   = (float*)(ws + 243269632);
    float* WtW    = (float*)(ws + 260046848);
    float* WtT    = (float*)(ws + 260050944);
    float* cvn    = (float*)(ws + 260067328);
    float* d0m    = (float*)(ws);               // reuse a_s region
    float* dec1   = (float*)(ws + 67108864);    // reuse a_s region (tail)

    // n-branch encoder (a_n dead after conv2s2_silu)
    conv1_silu<16><<<2048, 256, 0, stream>>>(x, e0n_w1, e0n_b1, a_n);
    conv2s2_silu<16, 16><<<512, 256, 0, stream>>>(a_n, e0n_w2, e0n_b2, z);
    // s-branch encoder: NC8HW8 MFMA conv1 -> MFMA implicit-GEMM conv2 (bf16 t_star out)
    wprep_kern<<<576, 256, 0, stream>>>(e0s_w2, wt2);
    conv1s_mfma<<<4096, 256, 0, stream>>>(x, e0s_w1, e0s_b1, a_s);
    conv2s_mfma<<<2048, 256, 0, stream>>>(a_s, wt2, e0s_b2, t_star);
    // memcell
    memcell_w_kern<<<512, 256, 0, stream>>>(z, cell_k, wmat);
    hipMemsetAsync(WtW, 0, (1024 + 4096) * sizeof(float), stream);
    memcell_acc_kern<<<1024, 256, 0, stream>>>(wmat, t_star, part);
    memcell_reduce_kern<<<320, 256, 0, stream>>>(part, WtT, WtW);
    cvnew_kern<<<16, 256, 0, stream>>>(cell_v, WtW, WtT, cvn);
    memcell_read_kern<<<512, 256, 0, stream>>>(wmat, cvn, d0m);
    // decoder
    deconv_silu_kern<<<512, 256, 0, stream>>>(d0m, d0_dw, d0_db, dec1);
    conv1_silu<3><<<2048, 256, 0, stream>>>(dec1, d0_cw, d0_cb, outp);
}